// Round 9
// baseline (322.881 us; speedup 1.0000x reference)
//
#include <hip/hip_runtime.h>

typedef __attribute__((ext_vector_type(8))) short bf16x8;
typedef __attribute__((ext_vector_type(8))) unsigned short u16x8;
typedef __attribute__((ext_vector_type(4))) float f32x4;

#define DEV static __device__ __forceinline__

// ---- config ----
constexpr int DM   = 128;
constexpr int DIN  = 256;
constexpr int NP   = 65;      // NPATCH
constexpr int NSEQ = 512;     // B*C
constexpr int HNF  = 8320;    // DM*NP
constexpr int LOPL = NSEQ*HNF;   // shorts between hi and lo planes

// ---- ws layout (float offsets) ----
// LIVENESS NOTE: PB region is fully clobbered by k_layer(0) output; nothing
// that must survive past k_layer(0) may live there except k_headp partials
// (written afterwards). No persistent counters exist in this layout.
constexpr size_t OFF_FLAG = 0;
constexpr size_t OFF_MEAN = 16;                       // 512
constexpr size_t OFF_STD  = OFF_MEAN + 512;           // 512
constexpr size_t OFF_ANEG = OFF_STD  + 512;           // 2*256*16 = 8192
constexpr size_t OFF_CONVW= OFF_ANEG + 8192;          // 2048
constexpr size_t OFF_CONVB= OFF_CONVW+ 2048;          // 512
constexpr size_t OFF_DTPB = OFF_CONVB+ 512;           // 512
constexpr size_t OFF_DD   = OFF_DTPB + 512;           // 512
constexpr size_t OFF_PEWT = OFF_DD   + 512;           // 2048
constexpr size_t OFF_PEB  = OFF_PEWT + 2048;          // 128
constexpr size_t OFF_INF  = OFF_PEB  + 128;           // 131072 shorts = 65536 f
constexpr size_t OFF_XPF  = OFF_INF  + 65536;         // 24576 shorts = 12288 f
constexpr size_t OFF_OPF  = OFF_XPF  + 12288;         // 65536 shorts = 32768 f
constexpr size_t OFF_HDF  = OFF_OPF  + 32768;         // 798720 shorts = 399360 f
constexpr size_t OFF_PA   = OFF_HDF  + 399360;        // hi+lo planes: 2*NSEQ*HNF shorts
constexpr size_t OFF_PB   = OFF_PA   + (size_t)NSEQ*HNF;
constexpr size_t OFF_HACC = OFF_PB;                   // head partials (written after layers)
// total = OFF_PB + NSEQ*HNF = 9,044,624 floats ~= 36.2 MB

DEV float b2f(unsigned short u){ union{unsigned v; float f;} x; x.v = ((unsigned)u)<<16; return x.f; }
DEV unsigned short f2b(float f){
  union{float f32; unsigned u;} x; x.f32 = f;
  unsigned r = x.u + 0x7fffu + ((x.u>>16)&1u);
  return (unsigned short)(r>>16);
}
DEV void split2(float v, unsigned short& h, unsigned short& l){
  h = f2b(v); l = f2b(v - b2f(h));
}
DEV float load_in(const void* p, size_t i, int isbf){
  return isbf ? b2f(((const unsigned short*)p)[i]) : ((const float*)p)[i];
}
DEV f32x4 mfma16(bf16x8 a, bf16x8 b, f32x4 c){
  return __builtin_amdgcn_mfma_f32_16x16x32_bf16(a,b,c,0,0,0);
}
constexpr float LOG2E = 1.4426950408889634f;
constexpr float LN2   = 0.6931471805599453f;
DEV float ex2(float x){ float r; asm("v_exp_f32 %0, %1" : "=v"(r) : "v"(x)); return r; }
DEV float lg2(float x){ float r; asm("v_log_f32 %0, %1" : "=v"(r) : "v"(x)); return r; }
DEV float frcp(float x){ float r; asm("v_rcp_f32 %0, %1" : "=v"(r) : "v"(x)); return r; }
DEV float sigm(float x){ return frcp(1.f + ex2(-x*LOG2E)); }
DEV float softplus(float x){
  float t = ex2(-fabsf(x)*LOG2E);
  return fmaxf(x,0.f) + LN2*lg2(1.f + t);
}
DEV int detect_bf16_wave(const void* x, int tid){
  const unsigned short* u = (const unsigned short*)x;
  unsigned short v = u[2*tid];
  int e = (v>>7)&0xff;
  int pred = (v==0) || (e>=100 && e<=141);
  unsigned long long m = __ballot(pred);
  return __popcll(m) >= 48;
}
// load 8 consecutive source elements (f32 or bf16) -> exact-bf16 u16x8
DEV u16x8 load8_cvt(const void* p, size_t off, int isbf){
  u16x8 o;
  if (isbf){
    o = *(const u16x8*)((const unsigned short*)p + off);   // identity (f2b∘b2f == id)
  } else {
    const float* s = (const float*)p + off;
    float4 a = *(const float4*)(s), b = *(const float4*)(s+4);
    o[0]=f2b(a.x); o[1]=f2b(a.y); o[2]=f2b(a.z); o[3]=f2b(a.w);
    o[4]=f2b(b.x); o[5]=f2b(b.y); o[6]=f2b(b.z); o[7]=f2b(b.w);
  }
  return o;
}

// =====================================================================
// fused prep + embed. repack blocks [0,NPREP), embed blocks [NPREP,NPREP+512)
// HDF repack kept (coalescing beats byte-count -- round-6 lesson).
// =====================================================================
constexpr size_t N_SMALL = 13952;                 // scalar f32 params
constexpr size_t N_IN8 = 16384, N_XP8 = 3072, N_OP8 = 8192, N_HD8 = 99840;
constexpr size_t N_BIG8 = N_IN8+N_XP8+N_OP8+N_HD8;  // 127488
constexpr int NPREP = (int)((N_SMALL + N_BIG8 + 255)/256);  // 553
__global__ void k_pre(const void* x_enc, const void* pe_w, const void* pe_b,
                      const void* in_w, const void* conv_w, const void* conv_b,
                      const void* xp_w, const void* dtp_b,
                      const void* A_log, const void* Dm, const void* op_w,
                      const void* head_w, float* __restrict__ ws)
{
  const int tid = threadIdx.x;
  __shared__ int sflag;
  __shared__ float sx[512];
  __shared__ float spe[16*128];
  __shared__ float spb[128];
  __shared__ float rs[8], rq[8], sm[2];

  if (tid < 64){
    int f = detect_bf16_wave(x_enc, tid);
    if (tid==0) sflag = f;
  }
  __syncthreads();
  const int isbf = sflag;

  if (blockIdx.x < NPREP){
    if (blockIdx.x==0 && tid==0) ws[OFF_FLAG] = (float)isbf;
    size_t i = (size_t)blockIdx.x*256 + tid;
    const size_t nA=8192, nCW=2048, nCB=512, nDB=512, nD=512, nPW=2048, nPB=128;
    if (i < N_SMALL){
      if (i < nA){ ws[OFF_ANEG+i] = -__expf(load_in(A_log,i,isbf)); return; } i -= nA;
      if (i < nCW){ ws[OFF_CONVW+i] = load_in(conv_w,i,isbf); return; } i -= nCW;
      if (i < nCB){ ws[OFF_CONVB+i] = load_in(conv_b,i,isbf); return; } i -= nCB;
      if (i < nDB){ ws[OFF_DTPB+i]  = load_in(dtp_b,i,isbf); return; } i -= nDB;
      if (i < nD){  ws[OFF_DD+i]    = load_in(Dm,i,isbf); return; } i -= nD;
      if (i < nPW){ size_t k=i>>7, dm=i&127; ws[OFF_PEWT+i]=load_in(pe_w, dm*16+k, isbf); return; } i -= nPW;
      ws[OFF_PEB+i] = load_in(pe_b,i,isbf); return;
    }
    size_t i8 = i - N_SMALL;
    if (i8 >= N_BIG8) return;
    if (i8 < N_IN8){ // in_proj: 8 shorts at frag idx i8*8; k contiguous
      size_t lane=i8&63, kk=(i8>>6)&3, nt=(i8>>8)&31, l=i8>>13;
      size_t e=nt*16+(lane&15), k0=kk*32+((lane>>4)*8);
      ((u16x8*)((unsigned short*)(ws+OFF_INF)))[i8] =
        load8_cvt(in_w, (l*512+e)*128 + k0, isbf);
      return;
    } i8 -= N_IN8;
    if (i8 < N_XP8){ // x_proj (o<40 real, else zero-pad)
      size_t lane=i8&63, kk=(i8>>6)&7; size_t rest=i8>>9;
      size_t nt=rest%3, l=rest/3;
      size_t o=nt*16+(lane&15), k0=kk*32+((lane>>4)*8);
      u16x8 v;
      if (o<40) v = load8_cvt(xp_w, (l*40+o)*256 + k0, isbf);
      else { u16x8 z = {0,0,0,0,0,0,0,0}; v = z; }
      ((u16x8*)((unsigned short*)(ws+OFF_XPF)))[i8] = v;
      return;
    } i8 -= N_XP8;
    if (i8 < N_OP8){ // out_proj
      size_t lane=i8&63, kk=(i8>>6)&7, nt=(i8>>9)&7, l=i8>>12;
      size_t dm=nt*16+(lane&15), k0=kk*32+((lane>>4)*8);
      ((u16x8*)((unsigned short*)(ws+OFF_OPF)))[i8] =
        load8_cvt(op_w, (l*128+dm)*256 + k0, isbf);
      return;
    } i8 -= N_OP8;
    { // head: B[k(8320)][pred(96)] = head_w[pred][k], [nt6][kk260]
      size_t lane=i8&63, t=i8>>6;
      size_t kk=t%260, nt=t/260;
      size_t pr=nt*16+(lane&15), k0=kk*32+((lane>>4)*8);
      ((u16x8*)((unsigned short*)(ws+OFF_HDF)))[i8] =
        load8_cvt(head_w, pr*8320 + k0, isbf);
      return;
    }
  }

  // ---------------- embed (RevIN + patch conv) ----------------
  const int n = blockIdx.x - NPREP;
  const int b = n>>4, c = n&15;

  float v0 = load_in(x_enc, ((size_t)b*512+tid)*16 + c, isbf);
  float v1 = load_in(x_enc, ((size_t)b*512+tid+256)*16 + c, isbf);
  float s = v0+v1, q = v0*v0+v1*v1;
  for (int o=32;o;o>>=1){ s += __shfl_down(s,o,64); q += __shfl_down(q,o,64); }
  const int w = tid>>6, lane = tid&63;
  if (lane==0){ rs[w]=s; rq[w]=q; }
  __syncthreads();
  if (tid==0){
    float S=rs[0]+rs[1]+rs[2]+rs[3], Q=rq[0]+rq[1]+rq[2]+rq[3];
    float mean = S*(1.f/512.f);
    float var = fmaxf(Q*(1.f/512.f)-mean*mean, 0.f);
    float sd = sqrtf(var+1e-5f);
    sm[0]=mean; sm[1]=1.f/sd;
    ws[OFF_MEAN+n]=mean; ws[OFF_STD+n]=sd;
  }
  __syncthreads();
  const float mean=sm[0], rstd=sm[1];
  sx[tid]=(v0-mean)*rstd; sx[tid+256]=(v1-mean)*rstd;
  for (int i=tid;i<2048;i+=256) spe[i]=load_in(pe_w, (size_t)(i&127)*16 + (i>>7), isbf);
  if (tid<128) spb[tid]=load_in(pe_b, tid, isbf);
  __syncthreads();

  unsigned short* pa_hi = (unsigned short*)(ws+OFF_PA);
  unsigned short* pa_lo = pa_hi + LOPL;
  for (int i=tid;i<NP*DM;i+=256){
    int t=i>>7, dm=i&127;
    float acc = spb[dm];
    int j0 = t*8-8;
    #pragma unroll
    for (int k=0;k<16;k++){ int j=j0+k; if ((unsigned)j<512u) acc += sx[j]*spe[k*128+dm]; }
    unsigned short h,lo2; split2(acc,h,lo2);
    pa_hi[(size_t)n*HNF+i] = h;
    pa_lo[(size_t)n*HNF+i] = lo2;
  }
}

// =====================================================================
// One fused Mamba layer, split-precision. block = one sequence, 8 waves.
// __launch_bounds__(512,2): VGPR cap 256 (round-2's (512,4) cap of 64 was
// the regression cause). LDS 79KB -> 2 blocks/CU -> 16 waves/CU.
// =====================================================================
__global__ __launch_bounds__(512,2)
void k_layer(int l, const unsigned short* __restrict__ pin,
             unsigned short* __restrict__ pout, float* __restrict__ ws,
             const void* __restrict__ dtp_w_raw)
{
  const int n = blockIdx.x, tid = threadIdx.x;
  const int w = tid>>6, lane = tid&63, ml = lane&15, quad = lane>>4;
  const int isbf = ws[OFF_FLAG] != 0.f;

  __shared__ __align__(16) unsigned char arena[79040];
  unsigned short* s_hi = (unsigned short*)arena;
  unsigned short* s_lo = (unsigned short*)(arena+34320);
  float* s_dbc = (float*)(arena+68640);
  constexpr int LOH = 17160;   // s_lo - s_hi in shorts

  const unsigned short* INF = (const unsigned short*)(ws+OFF_INF) + (size_t)l*65536;
  const unsigned short* XPF = (const unsigned short*)(ws+OFF_XPF) + (size_t)l*12288;
  const unsigned short* OPF = (const unsigned short*)(ws+OFF_OPF) + (size_t)l*32768;
  const unsigned short* phi = pin + (size_t)n*HNF;
  const unsigned short* plo = phi + LOPL;

  // ---- phase 1: in_proj xin-half (M=65,N=256,K=128); wave w owns nt=w*2,w*2+1
  {
    f32x4 acc[5][2];
    #pragma unroll
    for (int mt=0;mt<5;mt++){
      #pragma unroll
      for (int p2=0;p2<2;p2++){ f32x4 z={0.f,0.f,0.f,0.f}; acc[mt][p2]=z; }
    }
    bf16x8 ah[2][5], al[2][5];
    #pragma unroll
    for (int mt=0;mt<5;mt++){
      int row = mt*16+ml; if (row>64) row=64;
      ah[0][mt] = *(const bf16x8*)&phi[(size_t)row*128 + quad*8];
      al[0][mt] = *(const bf16x8*)&plo[(size_t)row*128 + quad*8];
    }
    #pragma unroll
    for (int kk=0;kk<4;kk++){
      const int cur = kk&1, nxt = cur^1;
      bf16x8 b0 = *(const bf16x8*)&INF[((size_t)((w*2+0)*4+kk))*512 + lane*8];
      bf16x8 b1 = *(const bf16x8*)&INF[((size_t)((w*2+1)*4+kk))*512 + lane*8];
      if (kk<3){
        #pragma unroll
        for (int mt=0;mt<5;mt++){
          int row = mt*16+ml; if (row>64) row=64;
          ah[nxt][mt] = *(const bf16x8*)&phi[(size_t)row*128 + (kk+1)*32 + quad*8];
          al[nxt][mt] = *(const bf16x8*)&plo[(size_t)row*128 + (kk+1)*32 + quad*8];
        }
      }
      #pragma unroll
      for (int mt=0;mt<5;mt++)
        acc[mt][0] = mfma16(ah[cur][mt],b0,mfma16(al[cur][mt],b0,acc[mt][0]));
      #pragma unroll
      for (int mt=0;mt<5;mt++)
        acc[mt][1] = mfma16(ah[cur][mt],b1,mfma16(al[cur][mt],b1,acc[mt][1]));
    }
    #pragma unroll
    for (int p2=0;p2<2;p2++){
      int e = (w*2 + p2)*16 + ml;
      #pragma unroll
      for (int mt=0;mt<5;mt++){
        #pragma unroll
        for (int r=0;r<4;r++){
          int t = mt*16+quad*4+r;
          if (t<NP){
            unsigned short h,lo2; split2(acc[mt][p2][r],h,lo2);
            s_hi[t*264+e]=h; s_lo[t*264+e]=lo2;
          }
        }
      }
    }
  }
  __syncthreads();

  // ---- phase 2: causal depthwise conv (k=4) + SiLU in place.
  // 512 threads: (d = tid&255, half = tid>>8); t-range split (FIR t-parallel).
  {
    const int d = tid & 255, half = tid >> 8;
    const float4 wv = ((const float4*)(ws+OFF_CONVW))[l*256+d];
    const float bb = ws[OFF_CONVB + l*256+d];
    float x0=0.f, x1=0.f, x2=0.f;
    if (half){  // warm-up taps: pre-conv inputs at t=30,31,32
      x0 = b2f(s_hi[30*264+d]) + b2f(s_lo[30*264+d]);
      x1 = b2f(s_hi[31*264+d]) + b2f(s_lo[31*264+d]);
      x2 = b2f(s_hi[32*264+d]) + b2f(s_lo[32*264+d]);
    }
    __syncthreads();   // warm-ups read before any in-place overwrite
    const int t0 = half ? 33 : 0, t1 = half ? NP : 33;
    int t = t0;
    for (; t+4<=t1; t+=4){
      float xi0 = b2f(s_hi[(t+0)*264+d]) + b2f(s_lo[(t+0)*264+d]);
      float xi1 = b2f(s_hi[(t+1)*264+d]) + b2f(s_lo[(t+1)*264+d]);
      float xi2 = b2f(s_hi[(t+2)*264+d]) + b2f(s_lo[(t+2)*264+d]);
      float xi3 = b2f(s_hi[(t+3)*264+d]) + b2f(s_lo[(t+3)*264+d]);
      float v0 = bb + wv.x*x0  + wv.y*x1  + wv.z*x2  + wv.w*xi0;
      float v1 = bb + wv.x*x1  + wv.y*x2  + wv.z*xi0 + wv.w*xi1;
      float v2 = bb + wv.x*x2  + wv.y*xi0 + wv.z*xi1 + wv.w*xi2;
      float v3 = bb + wv.x*xi0 + wv.y*xi1 + wv.z*xi2 + wv.w*xi3;
      x0=xi1; x1=xi2; x2=xi3;
      float s0 = v0*sigm(v0), s1 = v1*sigm(v1), s2 = v2*sigm(v2), s3 = v3*sigm(v3);
      unsigned short h,lo2;
      split2(s0,h,lo2); s_hi[(t+0)*264+d]=h; s_lo[(t+0)*264+d]=lo2;
      split2(s1,h,lo2); s_hi[(t+1)*264+d]=h; s_lo[(t+1)*264+d]=lo2;
      split2(s2,h,lo2); s_hi[(t+2)*264+d]=h; s_lo[(t+2)*264+d]=lo2;
      split2(s3,h,lo2); s_hi[(t+3)*264+d]=h; s_lo[(t+3)*264+d]=lo2;
    }
    for (; t<t1; ++t){
      float xi = b2f(s_hi[t*264+d]) + b2f(s_lo[t*264+d]);
      float v = bb + wv.x*x0 + wv.y*x1 + wv.z*x2 + wv.w*xi;
      x0=x1; x1=x2; x2=xi;
      float sv = v * sigm(v);
      unsigned short h,lo2; split2(sv,h,lo2);
      s_hi[t*264+d]=h; s_lo[t*264+d]=lo2;
    }
  }
  __syncthreads();

  // ---- phase 3: x_proj (M=65,N=48(40),K=256) split-A -> s_dbc fp32
  for (int tile=w; tile<15; tile+=8){
    int mt=tile/3, nt=tile%3;
    f32x4 acc={0.f,0.f,0.f,0.f};
    #pragma unroll
    for (int kk=0;kk<8;kk++){
      int row = mt*16+ml; if (row>64) row=64;
      bf16x8 ah = *(const bf16x8*)&s_hi[row*264 + kk*32 + quad*8];
      bf16x8 al = *(const bf16x8*)&s_lo[row*264 + kk*32 + quad*8];
      bf16x8 b  = *(const bf16x8*)&XPF[((size_t)(nt*8+kk))*512 + lane*8];
      acc = mfma16(ah,b,mfma16(al,b,acc));
    }
    int o = nt*16+ml;
    #pragma unroll
    for (int r=0;r<4;r++){
      int t=mt*16+quad*4+r;
      if (t<NP && o<40) s_dbc[t*40+o] = acc[r];
    }
  }
  __syncthreads();

  // ---- phase 4: dt + selective scan + D-skip.
  // 512 threads: pair (d = tid>>1, ho = tid&1); each owns 8 of 16 states.
  {
    const int d = (tid>>1) & 255;
    const int ho = tid & 1;
    float A2[8];
    {
      const float4* ap = (const float4*)(ws+OFF_ANEG) + ((size_t)l*256+d)*4 + ho*2;
      float4 ta = ap[0], tb = ap[1];
      A2[0]=ta.x*LOG2E; A2[1]=ta.y*LOG2E; A2[2]=ta.z*LOG2E; A2[3]=ta.w*LOG2E;
      A2[4]=tb.x*LOG2E; A2[5]=tb.y*LOG2E; A2[6]=tb.z*LOG2E; A2[7]=tb.w*LOG2E;
    }
    int fastbit = 1;
    #pragma unroll
    for (int ss=0;ss<8;ss++){
      int sidx = ho*8 + ss + 1;
      float ex = -(float)sidx*LOG2E;
      fastbit &= (fabsf(A2[ss]-ex) <= 1e-4f*(float)sidx) ? 1 : 0;
    }
    const int fastu = __all(fastbit);
    const float Dv = ws[OFF_DD + l*256+d];
    const float bias = ws[OFF_DTPB + l*256+d];
    float wdt[8];
    #pragma unroll
    for (int r=0;r<8;r++) wdt[r] = load_in(dtp_w_raw, ((size_t)l*256+d)*8+r, isbf);
    float h[8];
    #pragma unroll
    for (int ss=0;ss<8;ss++) h[ss]=0.f;

    float4 q0 = *(const float4*)&s_dbc[0];
    float4 q1 = *(const float4*)&s_dbc[4];
    float xh = b2f(s_hi[d]), xl = b2f(s_lo[d]);

    for (int t=0;t<NP;t++){
      const float* row = &s_dbc[t*40];
      float xv = xh + xl;
      const float* bp = row + 8 + ho*8;
      const float* cp = row + 24 + ho*8;
      float4 b0=*(const float4*)(bp), b1=*(const float4*)(bp+4);
      float4 c0=*(const float4*)(cp), c1=*(const float4*)(cp+4);
      float4 nq0, nq1; float nxh=0.f, nxl=0.f;
      if (t+1<NP){
        const float* nrow = &s_dbc[(t+1)*40];
        nq0 = *(const float4*)(nrow);
        nq1 = *(const float4*)(nrow+4);
        nxh = b2f(s_hi[(t+1)*264+d]); nxl = b2f(s_lo[(t+1)*264+d]);
      }
      float p0 = q0.x*wdt[0] + q0.y*wdt[1];
      float p1 = q0.z*wdt[2] + q0.w*wdt[3];
      float p2 = q1.x*wdt[4] + q1.y*wdt[5];
      float p3 = q1.z*wdt[6] + q1.w*wdt[7];
      float din = (bias + p0 + p1) + (p2 + p3);
      float dtv = softplus(din);
      float dtx = dtv*xv;
      float Bv[8], Cv[8];
      Bv[0]=b0.x;Bv[1]=b0.y;Bv[2]=b0.z;Bv[3]=b0.w; Bv[4]=b1.x;Bv[5]=b1.y;Bv[6]=b1.z;Bv[7]=b1.w;
      Cv[0]=c0.x;Cv[1]=c0.y;Cv[2]=c0.z;Cv[3]=c0.w; Cv[4]=c1.x;Cv[5]=c1.y;Cv[6]=c1.z;Cv[7]=c1.w;
      float rr[8];
      if (fastu){
        float r1 = ex2(-dtv*LOG2E);
        float r2=r1*r1, r3=r2*r1, r4=r2*r2;
        float r5=r4*r1, r6=r4*r2, r7=r4*r3, r8=r4*r4;
        float rp = ho ? r8 : 1.f;
        rr[0]=r1*rp; rr[1]=r2*rp; rr[2]=r3*rp; rr[3]=r4*rp;
        rr[4]=r5*rp; rr[5]=r6*rp; rr[6]=r7*rp; rr[7]=r8*rp;
      } else {
        #pragma unroll
        for (int ss=0;ss<8;ss++) rr[ss] = ex2(dtv*A2[ss]);
      }
      float y0 = 0.f, y1 = 0.f;
      #pragma unroll
      for (int ss=0;ss<8;ss+=2){
        h[ss]   = rr[ss]*h[ss]     + dtx*Bv[ss];
        h[ss+1] = rr[ss+1]*h[ss+1] + dtx*Bv[ss+1];
        y0 += h[ss]*Cv[ss];
        y1 += h[ss+1]*Cv[ss+1];
      }
      float y = y0 + y1;
      y += __shfl_xor(y, 1, 64);      // partner holds the other 8 states
      float g0 = y + xv*Dv;
      unsigned short hh,lo2; split2(g0,hh,lo2);
      unsigned short vv = ho ? lo2 : hh;
      s_hi[t*264 + d + ho*LOH] = vv;  // ho=0 -> hi plane, ho=1 -> lo plane
      q0=nq0; q1=nq1; xh=nxh; xl=nxl;
    }
  }
  __syncthreads();

  // ---- phase 5: z-half GEMM (recompute) + fused silu-gating in place.
  // mt-outer/nt-inner with next-mt A prefetch; 16 nt over 8 waves (j<2).
  {
    bf16x8 ah[2][4], al[2][4];
    {
      int row = ml; // mt=0
      #pragma unroll
      for (int kk=0;kk<4;kk++){
        ah[0][kk] = *(const bf16x8*)&phi[(size_t)row*128 + kk*32 + quad*8];
        al[0][kk] = *(const bf16x8*)&plo[(size_t)row*128 + kk*32 + quad*8];
      }
    }
    #pragma unroll
    for (int mt=0; mt<5; ++mt){
      const int cur = mt&1, nxt = cur^1;
      if (mt<4){
        int row = (mt+1)*16+ml; if (row>64) row=64;
        #pragma unroll
        for (int kk=0;kk<4;kk++){
          ah[nxt][kk] = *(const bf16x8*)&phi[(size_t)row*128 + kk*32 + quad*8];
          al[nxt][kk] = *(const bf16x8*)&plo[(size_t)row*128 + kk*32 + quad*8];
        }
      }
      #pragma unroll
      for (int j=0;j<2;j++){
        int nt = w + j*8;
        f32x4 acc={0.f,0.f,0.f,0.f};
        #pragma unroll
        for (int kk=0;kk<4;kk++){
          bf16x8 b = *(const bf16x8*)&INF[((size_t)((16+nt)*4+kk))*512 + lane*8];
          acc = mfma16(ah[cur][kk],b,mfma16(al[cur][kk],b,acc));
        }
        int d = nt*16+ml;
        #pragma unroll
        for (int r=0;r<4;r++){
          int t = mt*16+quad*4+r;
          if (t<NP){
            float g0 = b2f(s_hi[t*264+d]) + b2f(s_lo[t*264+d]);
            float zv = acc[r];
            float g = g0 * zv * sigm(zv);
            unsigned short hh,lo2; split2(g,hh,lo2);
            s_hi[t*264+d]=hh; s_lo[t*264+d]=lo2;
          }
        }
      }
    }
  }
  __syncthreads();

  // ---- phase 6: out_proj (M=65,N=128,K=256); wave w owns dm-tile w.
  {
    f32x4 acc[5];
    #pragma unroll
    for (int mt=0;mt<5;mt++){ f32x4 z={0.f,0.f,0.f,0.f}; acc[mt]=z; }
    bf16x8 bpre[2];
    bpre[0] = *(const bf16x8*)&OPF[((size_t)(w*8+0))*512 + lane*8];
    #pragma unroll
    for (int kk=0;kk<8;kk++){
      const int cur = kk&1, nxt = cur^1;
      if (kk<7)
        bpre[nxt] = *(const bf16x8*)&OPF[((size_t)(w*8+kk+1))*512 + lane*8];
      bf16x8 ah[5], al[5];
      #pragma unroll
      for (int mt=0;mt<5;mt++){
        int row = mt*16+ml; if (row>64) row=64;
        ah[mt] = *(const bf16x8*)&s_hi[row*264 + kk*32 + quad*8];
        al[mt] = *(const bf16x8*)&s_lo[row*264 + kk*32 + quad*8];
      }
      #pragma unroll
      for (int mt=0;mt<5;mt++)
        acc[mt] = mfma16(ah[mt],bpre[cur],mfma16(al[mt],bpre[cur],acc[mt]));
    }
    int dm = w*16+ml;
    #pragma unroll
    for (int mt=0;mt<5;mt++){
      #pragma unroll
      for (int r=0;r<4;r++){
        int t = mt*16+quad*4+r;
        if (t<NP){
          unsigned short hh,lo2; split2(acc[mt][r],hh,lo2);
          pout[(size_t)n*HNF + t*128 + dm] = hh;
          pout[(size_t)n*HNF + t*128 + dm + LOPL] = lo2;
        }
      }
    }
  }
}

// =====================================================================
// head GEMM, K-split x4: coalesced HDF B + prefetch; partials -> OFF_HACC
// =====================================================================
__global__ void k_headp(const float* __restrict__ ws, float* __restrict__ hacc)
{
  const int blk = blockIdx.x;
  const int p = blk & 3, tile = blk >> 2;
  const int nt = tile%6, mt = tile/6;
  const int tid = threadIdx.x, w = tid>>6, lane = tid&63, ml = lane&15, quad = lane>>4;
  const unsigned short* pa_hi = (const unsigned short*)(ws+OFF_PA);
  const unsigned short* pa_lo = pa_hi + LOPL;
  const unsigned short* HDF = (const unsigned short*)(ws+OFF_HDF);
  __shared__ float red[4][64][4];

  f32x4 acc={0.f,0.f,0.f,0.f};
  const size_t abase = (size_t)(mt*16+ml)*HNF + quad*8;
  // software-pipelined K loop
  int i = w;
  int kk = p*65 + i;
  bf16x8 ah = *(const bf16x8*)(pa_hi + abase + (size_t)kk*32);
  bf16x8 al = *(const bf16x8*)(pa_lo + abase + (size_t)kk*32);
  bf16x8 b  = *(const bf16x8*)&HDF[((size_t)(nt*260+kk))*512 + lane*8];
  while (i < 65){
    const int inext = i + 4;
    bf16x8 nah, nal, nb;
    if (inext < 65){
      int nkk = p*65 + inext;
      nah = *(const bf16x8*)(pa_hi + abase + (size_t)nkk*32);
      nal = *(const bf16x8*)(pa_lo + abase + (size_t)nkk*32);
      nb  = *(const bf16x8*)&HDF[((size_t)(nt*260+nkk))*512 + lane*8];
    }
    acc = mfma16(ah,b,mfma16(al,b,acc));
    ah=nah; al=nal; b=nb; i=inext;
  }
  #pragma unroll
  for (int r=0;r<4;r++) red[w][lane][r]=acc[r];
  __syncthreads();
  if (w==0){
    #pragma unroll
    for (int r=0;r<4;r++){
      float s = red[0][lane][r]+red[1][lane][r]+red[2][lane][r]+red[3][lane][r];
      hacc[((size_t)tile*4 + p)*256 + lane*4 + r] = s;
    }
  }
}

// =====================================================================
// final: sum 4 partials + de-norm + write out. 192 blocks x 64 threads.
// =====================================================================
__global__ void k_fin(const float* __restrict__ ws, void* __restrict__ out)
{
  const int tile = blockIdx.x;
  const int nt = tile%6, mt = tile/6;
  const int lane = threadIdx.x, ml = lane&15, quad = lane>>4;
  const float* hacc = ws + OFF_HACC;
  const int isbf = ws[OFF_FLAG]!=0.f;
  #pragma unroll
  for (int r=0;r<4;r++){
    size_t base = (size_t)tile*4*256 + lane*4 + r;
    float s = hacc[base] + hacc[base+256] + hacc[base+512] + hacc[base+768];
    int nseq = mt*16 + quad*4 + r;
    int pred = nt*16 + ml;
    float val = s*ws[OFF_STD+nseq] + ws[OFF_MEAN+nseq];
    size_t o = ((size_t)(nseq>>4)*96 + pred)*16 + (nseq&15);
    if (isbf) ((unsigned short*)out)[o] = f2b(val);
    else      ((float*)out)[o] = val;
  }
}

extern "C" void kernel_launch(void* const* d_in, const int* in_sizes, int n_in,
                              void* d_out, int out_size, void* d_ws, size_t ws_size,
                              hipStream_t stream)
{
  (void)in_sizes; (void)n_in; (void)out_size; (void)ws_size;
  float* ws = (float*)d_ws;
  const void* x_enc = d_in[0];
  const void* pe_w  = d_in[2];  const void* pe_b  = d_in[3];
  const void* in_w  = d_in[4];  const void* conv_w= d_in[5];
  const void* conv_b= d_in[6];  const void* xp_w  = d_in[7];
  const void* dtp_w = d_in[8];  const void* dtp_b = d_in[9];
  const void* A_log = d_in[10]; const void* Dm    = d_in[11];
  const void* op_w  = d_in[12]; const void* head_w= d_in[13];

  k_pre<<<NPREP+NSEQ,256,0,stream>>>(x_enc,pe_w,pe_b,in_w,conv_w,conv_b,xp_w,
                                     dtp_b,A_log,Dm,op_w,head_w,ws);
  unsigned short* pa = (unsigned short*)(ws+OFF_PA);
  unsigned short* pb = (unsigned short*)(ws+OFF_PB);
  k_layer<<<NSEQ,512,0,stream>>>(0,pa,pb,ws,dtp_w);
  k_layer<<<NSEQ,512,0,stream>>>(1,pb,pa,ws,dtp_w);
  k_headp<<<768,256,0,stream>>>(ws, ws+OFF_HACC);
  k_fin<<<192,64,0,stream>>>(ws, d_out);
}

// Round 10
// 265.821 us; speedup vs baseline: 1.2147x; 1.2147x over previous
//
#include <hip/hip_runtime.h>

typedef __attribute__((ext_vector_type(8))) short bf16x8;
typedef __attribute__((ext_vector_type(8))) unsigned short u16x8;
typedef __attribute__((ext_vector_type(4))) float f32x4;

#define DEV static __device__ __forceinline__

// ---- config ----
constexpr int DM   = 128;
constexpr int DIN  = 256;
constexpr int NP   = 65;      // NPATCH
constexpr int NSEQ = 512;     // B*C
constexpr int HNF  = 8320;    // DM*NP
constexpr int LOPL = NSEQ*HNF;   // shorts between hi and lo planes

// ---- ws layout (float offsets) ----
// LIVENESS NOTE: PB region is fully clobbered by k_layer(0) output; nothing
// that must survive past k_layer(0) may live there except k_headp partials
// (written afterwards). No persistent counters exist in this layout.
constexpr size_t OFF_FLAG = 0;
constexpr size_t OFF_MEAN = 16;                       // 512
constexpr size_t OFF_STD  = OFF_MEAN + 512;           // 512
constexpr size_t OFF_ANEG = OFF_STD  + 512;           // 2*256*16 = 8192
constexpr size_t OFF_CONVW= OFF_ANEG + 8192;          // 2048
constexpr size_t OFF_CONVB= OFF_CONVW+ 2048;          // 512
constexpr size_t OFF_DTPB = OFF_CONVB+ 512;           // 512
constexpr size_t OFF_DD   = OFF_DTPB + 512;           // 512
constexpr size_t OFF_PEWT = OFF_DD   + 512;           // 2048
constexpr size_t OFF_PEB  = OFF_PEWT + 2048;          // 128
constexpr size_t OFF_INF  = OFF_PEB  + 128;           // 131072 shorts = 65536 f
constexpr size_t OFF_XPF  = OFF_INF  + 65536;         // 24576 shorts = 12288 f
constexpr size_t OFF_OPF  = OFF_XPF  + 12288;         // 65536 shorts = 32768 f
constexpr size_t OFF_HDF  = OFF_OPF  + 32768;         // 798720 shorts = 399360 f
constexpr size_t OFF_PA   = OFF_HDF  + 399360;        // hi+lo planes: 2*NSEQ*HNF shorts
constexpr size_t OFF_PB   = OFF_PA   + (size_t)NSEQ*HNF;
constexpr size_t OFF_HACC = OFF_PB;                   // head partials (written after layers)
// total = OFF_PB + NSEQ*HNF = 9,044,624 floats ~= 36.2 MB

DEV float b2f(unsigned short u){ union{unsigned v; float f;} x; x.v = ((unsigned)u)<<16; return x.f; }
DEV unsigned short f2b(float f){
  union{float f32; unsigned u;} x; x.f32 = f;
  unsigned r = x.u + 0x7fffu + ((x.u>>16)&1u);
  return (unsigned short)(r>>16);
}
DEV void split2(float v, unsigned short& h, unsigned short& l){
  h = f2b(v); l = f2b(v - b2f(h));
}
DEV float load_in(const void* p, size_t i, int isbf){
  return isbf ? b2f(((const unsigned short*)p)[i]) : ((const float*)p)[i];
}
DEV f32x4 mfma16(bf16x8 a, bf16x8 b, f32x4 c){
  return __builtin_amdgcn_mfma_f32_16x16x32_bf16(a,b,c,0,0,0);
}
constexpr float LOG2E = 1.4426950408889634f;
constexpr float LN2   = 0.6931471805599453f;
DEV float ex2(float x){ float r; asm("v_exp_f32 %0, %1" : "=v"(r) : "v"(x)); return r; }
DEV float lg2(float x){ float r; asm("v_log_f32 %0, %1" : "=v"(r) : "v"(x)); return r; }
DEV float frcp(float x){ float r; asm("v_rcp_f32 %0, %1" : "=v"(r) : "v"(x)); return r; }
DEV float sigm(float x){ return frcp(1.f + ex2(-x*LOG2E)); }
DEV float softplus(float x){
  float t = ex2(-fabsf(x)*LOG2E);
  return fmaxf(x,0.f) + LN2*lg2(1.f + t);
}
DEV int detect_bf16_wave(const void* x, int tid){
  const unsigned short* u = (const unsigned short*)x;
  unsigned short v = u[2*tid];
  int e = (v>>7)&0xff;
  int pred = (v==0) || (e>=100 && e<=141);
  unsigned long long m = __ballot(pred);
  return __popcll(m) >= 48;
}
// load 8 consecutive source elements (f32 or bf16) -> exact-bf16 u16x8
DEV u16x8 load8_cvt(const void* p, size_t off, int isbf){
  u16x8 o;
  if (isbf){
    o = *(const u16x8*)((const unsigned short*)p + off);   // identity (f2b∘b2f == id)
  } else {
    const float* s = (const float*)p + off;
    float4 a = *(const float4*)(s), b = *(const float4*)(s+4);
    o[0]=f2b(a.x); o[1]=f2b(a.y); o[2]=f2b(a.z); o[3]=f2b(a.w);
    o[4]=f2b(b.x); o[5]=f2b(b.y); o[6]=f2b(b.z); o[7]=f2b(b.w);
  }
  return o;
}

// =====================================================================
// fused prep + embed. repack blocks [0,NPREP), embed blocks [NPREP,NPREP+512)
// HDF repack kept (coalescing beats byte-count -- round-6 lesson).
// =====================================================================
constexpr size_t N_SMALL = 13952;                 // scalar f32 params
constexpr size_t N_IN8 = 16384, N_XP8 = 3072, N_OP8 = 8192, N_HD8 = 99840;
constexpr size_t N_BIG8 = N_IN8+N_XP8+N_OP8+N_HD8;  // 127488
constexpr int NPREP = (int)((N_SMALL + N_BIG8 + 255)/256);  // 553
__global__ void k_pre(const void* x_enc, const void* pe_w, const void* pe_b,
                      const void* in_w, const void* conv_w, const void* conv_b,
                      const void* xp_w, const void* dtp_b,
                      const void* A_log, const void* Dm, const void* op_w,
                      const void* head_w, float* __restrict__ ws)
{
  const int tid = threadIdx.x;
  __shared__ int sflag;
  __shared__ float sx[512];
  __shared__ float spe[16*128];
  __shared__ float spb[128];
  __shared__ float rs[8], rq[8], sm[2];

  if (tid < 64){
    int f = detect_bf16_wave(x_enc, tid);
    if (tid==0) sflag = f;
  }
  __syncthreads();
  const int isbf = sflag;

  if (blockIdx.x < NPREP){
    if (blockIdx.x==0 && tid==0) ws[OFF_FLAG] = (float)isbf;
    size_t i = (size_t)blockIdx.x*256 + tid;
    const size_t nA=8192, nCW=2048, nCB=512, nDB=512, nD=512, nPW=2048, nPB=128;
    if (i < N_SMALL){
      if (i < nA){ ws[OFF_ANEG+i] = -__expf(load_in(A_log,i,isbf)); return; } i -= nA;
      if (i < nCW){ ws[OFF_CONVW+i] = load_in(conv_w,i,isbf); return; } i -= nCW;
      if (i < nCB){ ws[OFF_CONVB+i] = load_in(conv_b,i,isbf); return; } i -= nCB;
      if (i < nDB){ ws[OFF_DTPB+i]  = load_in(dtp_b,i,isbf); return; } i -= nDB;
      if (i < nD){  ws[OFF_DD+i]    = load_in(Dm,i,isbf); return; } i -= nD;
      if (i < nPW){ size_t k=i>>7, dm=i&127; ws[OFF_PEWT+i]=load_in(pe_w, dm*16+k, isbf); return; } i -= nPW;
      ws[OFF_PEB+i] = load_in(pe_b,i,isbf); return;
    }
    size_t i8 = i - N_SMALL;
    if (i8 >= N_BIG8) return;
    if (i8 < N_IN8){ // in_proj: 8 shorts at frag idx i8*8; k contiguous
      size_t lane=i8&63, kk=(i8>>6)&3, nt=(i8>>8)&31, l=i8>>13;
      size_t e=nt*16+(lane&15), k0=kk*32+((lane>>4)*8);
      ((u16x8*)((unsigned short*)(ws+OFF_INF)))[i8] =
        load8_cvt(in_w, (l*512+e)*128 + k0, isbf);
      return;
    } i8 -= N_IN8;
    if (i8 < N_XP8){ // x_proj (o<40 real, else zero-pad)
      size_t lane=i8&63, kk=(i8>>6)&7; size_t rest=i8>>9;
      size_t nt=rest%3, l=rest/3;
      size_t o=nt*16+(lane&15), k0=kk*32+((lane>>4)*8);
      u16x8 v;
      if (o<40) v = load8_cvt(xp_w, (l*40+o)*256 + k0, isbf);
      else { u16x8 z = {0,0,0,0,0,0,0,0}; v = z; }
      ((u16x8*)((unsigned short*)(ws+OFF_XPF)))[i8] = v;
      return;
    } i8 -= N_XP8;
    if (i8 < N_OP8){ // out_proj
      size_t lane=i8&63, kk=(i8>>6)&7, nt=(i8>>9)&7, l=i8>>12;
      size_t dm=nt*16+(lane&15), k0=kk*32+((lane>>4)*8);
      ((u16x8*)((unsigned short*)(ws+OFF_OPF)))[i8] =
        load8_cvt(op_w, (l*128+dm)*256 + k0, isbf);
      return;
    } i8 -= N_OP8;
    { // head: B[k(8320)][pred(96)] = head_w[pred][k], [nt6][kk260]
      size_t lane=i8&63, t=i8>>6;
      size_t kk=t%260, nt=t/260;
      size_t pr=nt*16+(lane&15), k0=kk*32+((lane>>4)*8);
      ((u16x8*)((unsigned short*)(ws+OFF_HDF)))[i8] =
        load8_cvt(head_w, pr*8320 + k0, isbf);
      return;
    }
  }

  // ---------------- embed (RevIN + patch conv) ----------------
  const int n = blockIdx.x - NPREP;
  const int b = n>>4, c = n&15;

  float v0 = load_in(x_enc, ((size_t)b*512+tid)*16 + c, isbf);
  float v1 = load_in(x_enc, ((size_t)b*512+tid+256)*16 + c, isbf);
  float s = v0+v1, q = v0*v0+v1*v1;
  for (int o=32;o;o>>=1){ s += __shfl_down(s,o,64); q += __shfl_down(q,o,64); }
  const int w = tid>>6, lane = tid&63;
  if (lane==0){ rs[w]=s; rq[w]=q; }
  __syncthreads();
  if (tid==0){
    float S=rs[0]+rs[1]+rs[2]+rs[3], Q=rq[0]+rq[1]+rq[2]+rq[3];
    float mean = S*(1.f/512.f);
    float var = fmaxf(Q*(1.f/512.f)-mean*mean, 0.f);
    float sd = sqrtf(var+1e-5f);
    sm[0]=mean; sm[1]=1.f/sd;
    ws[OFF_MEAN+n]=mean; ws[OFF_STD+n]=sd;
  }
  __syncthreads();
  const float mean=sm[0], rstd=sm[1];
  sx[tid]=(v0-mean)*rstd; sx[tid+256]=(v1-mean)*rstd;
  for (int i=tid;i<2048;i+=256) spe[i]=load_in(pe_w, (size_t)(i&127)*16 + (i>>7), isbf);
  if (tid<128) spb[tid]=load_in(pe_b, tid, isbf);
  __syncthreads();

  unsigned short* pa_hi = (unsigned short*)(ws+OFF_PA);
  unsigned short* pa_lo = pa_hi + LOPL;
  for (int i=tid;i<NP*DM;i+=256){
    int t=i>>7, dm=i&127;
    float acc = spb[dm];
    int j0 = t*8-8;
    #pragma unroll
    for (int k=0;k<16;k++){ int j=j0+k; if ((unsigned)j<512u) acc += sx[j]*spe[k*128+dm]; }
    unsigned short h,lo2; split2(acc,h,lo2);
    pa_hi[(size_t)n*HNF+i] = h;
    pa_lo[(size_t)n*HNF+i] = lo2;
  }
}

// =====================================================================
// One fused Mamba layer, split-precision. block = one sequence.
// FINAL 256-thread structure (measured 74-76 us; 512-thread variants
// measured worse twice -- rounds 2 and 9: work duplication > occupancy).
// =====================================================================
__global__ __launch_bounds__(256,2)
void k_layer(int l, const unsigned short* __restrict__ pin,
             unsigned short* __restrict__ pout, float* __restrict__ ws,
             const void* __restrict__ dtp_w_raw)
{
  const int n = blockIdx.x, tid = threadIdx.x;
  const int w = tid>>6, lane = tid&63, ml = lane&15, quad = lane>>4;
  const int isbf = ws[OFF_FLAG] != 0.f;

  __shared__ __align__(16) unsigned char arena[79040];
  unsigned short* s_hi = (unsigned short*)arena;
  unsigned short* s_lo = (unsigned short*)(arena+34320);
  float* s_dbc = (float*)(arena+68640);

  const unsigned short* INF = (const unsigned short*)(ws+OFF_INF) + (size_t)l*65536;
  const unsigned short* XPF = (const unsigned short*)(ws+OFF_XPF) + (size_t)l*12288;
  const unsigned short* OPF = (const unsigned short*)(ws+OFF_OPF) + (size_t)l*32768;
  const unsigned short* phi = pin + (size_t)n*HNF;
  const unsigned short* plo = phi + LOPL;

  // ---- phase 1: in_proj xin-half (M=65,N=256,K=128), split-A -> s_hi/s_lo
  for (int pass=0; pass<2; ++pass){
    f32x4 acc[5][2];
    #pragma unroll
    for (int mt=0;mt<5;mt++){
      #pragma unroll
      for (int p2=0;p2<2;p2++){ f32x4 z={0.f,0.f,0.f,0.f}; acc[mt][p2]=z; }
    }
    bf16x8 ah[2][5], al[2][5];
    #pragma unroll
    for (int mt=0;mt<5;mt++){
      int row = mt*16+ml; if (row>64) row=64;
      ah[0][mt] = *(const bf16x8*)&phi[(size_t)row*128 + quad*8];
      al[0][mt] = *(const bf16x8*)&plo[(size_t)row*128 + quad*8];
    }
    #pragma unroll
    for (int kk=0;kk<4;kk++){
      const int cur = kk&1, nxt = cur^1;
      bf16x8 b0 = *(const bf16x8*)&INF[((size_t)((pass*8+w*2+0)*4+kk))*512 + lane*8];
      bf16x8 b1 = *(const bf16x8*)&INF[((size_t)((pass*8+w*2+1)*4+kk))*512 + lane*8];
      if (kk<3){
        #pragma unroll
        for (int mt=0;mt<5;mt++){
          int row = mt*16+ml; if (row>64) row=64;
          ah[nxt][mt] = *(const bf16x8*)&phi[(size_t)row*128 + (kk+1)*32 + quad*8];
          al[nxt][mt] = *(const bf16x8*)&plo[(size_t)row*128 + (kk+1)*32 + quad*8];
        }
      }
      #pragma unroll
      for (int mt=0;mt<5;mt++)
        acc[mt][0] = mfma16(ah[cur][mt],b0,mfma16(al[cur][mt],b0,acc[mt][0]));
      #pragma unroll
      for (int mt=0;mt<5;mt++)
        acc[mt][1] = mfma16(ah[cur][mt],b1,mfma16(al[cur][mt],b1,acc[mt][1]));
    }
    #pragma unroll
    for (int p2=0;p2<2;p2++){
      int e = (pass*8 + w*2 + p2)*16 + ml;
      #pragma unroll
      for (int mt=0;mt<5;mt++){
        #pragma unroll
        for (int r=0;r<4;r++){
          int t = mt*16+quad*4+r;
          if (t<NP){
            unsigned short h,lo2; split2(acc[mt][p2][r],h,lo2);
            s_hi[t*264+e]=h; s_lo[t*264+e]=lo2;
          }
        }
      }
    }
  }
  __syncthreads();

  // ---- phase 2: causal depthwise conv (k=4) + SiLU in place; thread=d.
  {
    const int d = tid;
    const float4 wv = ((const float4*)(ws+OFF_CONVW))[l*256+d];
    const float bb = ws[OFF_CONVB + l*256+d];
    float x0=0.f,x1=0.f,x2=0.f;
    int t = 0;
    for (; t+4<=NP; t+=4){
      float xi0 = b2f(s_hi[(t+0)*264+d]) + b2f(s_lo[(t+0)*264+d]);
      float xi1 = b2f(s_hi[(t+1)*264+d]) + b2f(s_lo[(t+1)*264+d]);
      float xi2 = b2f(s_hi[(t+2)*264+d]) + b2f(s_lo[(t+2)*264+d]);
      float xi3 = b2f(s_hi[(t+3)*264+d]) + b2f(s_lo[(t+3)*264+d]);
      float v0 = bb + wv.x*x0  + wv.y*x1  + wv.z*x2  + wv.w*xi0;
      float v1 = bb + wv.x*x1  + wv.y*x2  + wv.z*xi0 + wv.w*xi1;
      float v2 = bb + wv.x*x2  + wv.y*xi0 + wv.z*xi1 + wv.w*xi2;
      float v3 = bb + wv.x*xi0 + wv.y*xi1 + wv.z*xi2 + wv.w*xi3;
      x0=xi1; x1=xi2; x2=xi3;
      float s0 = v0*sigm(v0), s1 = v1*sigm(v1), s2 = v2*sigm(v2), s3 = v3*sigm(v3);
      unsigned short h,lo2;
      split2(s0,h,lo2); s_hi[(t+0)*264+d]=h; s_lo[(t+0)*264+d]=lo2;
      split2(s1,h,lo2); s_hi[(t+1)*264+d]=h; s_lo[(t+1)*264+d]=lo2;
      split2(s2,h,lo2); s_hi[(t+2)*264+d]=h; s_lo[(t+2)*264+d]=lo2;
      split2(s3,h,lo2); s_hi[(t+3)*264+d]=h; s_lo[(t+3)*264+d]=lo2;
    }
    for (; t<NP; ++t){
      float xi = b2f(s_hi[t*264+d]) + b2f(s_lo[t*264+d]);
      float v = bb + wv.x*x0 + wv.y*x1 + wv.z*x2 + wv.w*xi;
      x0=x1; x1=x2; x2=xi;
      float sv = v * sigm(v);
      unsigned short h,lo2; split2(sv,h,lo2);
      s_hi[t*264+d]=h; s_lo[t*264+d]=lo2;
    }
  }
  __syncthreads();

  // ---- phase 3: x_proj (M=65,N=48(40),K=256) split-A -> s_dbc fp32
  for (int tile=w; tile<15; tile+=4){
    int mt=tile/3, nt=tile%3;
    f32x4 acc={0.f,0.f,0.f,0.f};
    #pragma unroll
    for (int kk=0;kk<8;kk++){
      int row = mt*16+ml; if (row>64) row=64;
      bf16x8 ah = *(const bf16x8*)&s_hi[row*264 + kk*32 + quad*8];
      bf16x8 al = *(const bf16x8*)&s_lo[row*264 + kk*32 + quad*8];
      bf16x8 b  = *(const bf16x8*)&XPF[((size_t)(nt*8+kk))*512 + lane*8];
      acc = mfma16(ah,b,mfma16(al,b,acc));
    }
    int o = nt*16+ml;
    #pragma unroll
    for (int r=0;r<4;r++){
      int t=mt*16+quad*4+r;
      if (t<NP && o<40) s_dbc[t*40+o] = acc[r];
    }
  }
  __syncthreads();

  // ---- phase 4: dt (fp32) + selective scan + D-skip; thread=d.
  {
    const int d = tid;
    float A2[16];
    {
      const float4* ap = (const float4*)(ws+OFF_ANEG) + ((size_t)l*256+d)*4;
      #pragma unroll
      for (int qq=0;qq<4;qq++){
        float4 t4 = ap[qq];
        A2[qq*4]=t4.x*LOG2E; A2[qq*4+1]=t4.y*LOG2E; A2[qq*4+2]=t4.z*LOG2E; A2[qq*4+3]=t4.w*LOG2E;
      }
    }
    int fastbit = 1;
    #pragma unroll
    for (int ss=0;ss<16;ss++){
      float ex = -(float)(ss+1)*LOG2E;
      fastbit &= (fabsf(A2[ss]-ex) <= 1e-4f*(float)(ss+1)) ? 1 : 0;
    }
    const int fastu = __all(fastbit);
    const float Dv = ws[OFF_DD + l*256+d];
    const float bias = ws[OFF_DTPB + l*256+d];
    float wdt[8];
    #pragma unroll
    for (int r=0;r<8;r++) wdt[r] = load_in(dtp_w_raw, ((size_t)l*256+d)*8+r, isbf);
    float h[16];
    #pragma unroll
    for (int ss=0;ss<16;ss++) h[ss]=0.f;

    float4 q0 = *(const float4*)&s_dbc[0];
    float4 q1 = *(const float4*)&s_dbc[4];
    float xh = b2f(s_hi[d]), xl = b2f(s_lo[d]);

    for (int t=0;t<NP;t++){
      const float* row = &s_dbc[t*40];
      float xv = xh + xl;
      float4 b0=*(const float4*)(row+8),  b1=*(const float4*)(row+12),
             b2v=*(const float4*)(row+16), b3=*(const float4*)(row+20);
      float4 c0=*(const float4*)(row+24), c1=*(const float4*)(row+28),
             c2=*(const float4*)(row+32), c3=*(const float4*)(row+36);
      float4 nq0, nq1; float nxh=0.f, nxl=0.f;
      if (t+1<NP){
        const float* nrow = &s_dbc[(t+1)*40];
        nq0 = *(const float4*)(nrow);
        nq1 = *(const float4*)(nrow+4);
        nxh = b2f(s_hi[(t+1)*264+d]); nxl = b2f(s_lo[(t+1)*264+d]);
      }
      float p0 = q0.x*wdt[0] + q0.y*wdt[1];
      float p1 = q0.z*wdt[2] + q0.w*wdt[3];
      float p2 = q1.x*wdt[4] + q1.y*wdt[5];
      float p3 = q1.z*wdt[6] + q1.w*wdt[7];
      float din = (bias + p0 + p1) + (p2 + p3);
      float dtv = softplus(din);
      float dtx = dtv*xv;
      float Bv[16], Cv[16];
      Bv[0]=b0.x;Bv[1]=b0.y;Bv[2]=b0.z;Bv[3]=b0.w; Bv[4]=b1.x;Bv[5]=b1.y;Bv[6]=b1.z;Bv[7]=b1.w;
      Bv[8]=b2v.x;Bv[9]=b2v.y;Bv[10]=b2v.z;Bv[11]=b2v.w; Bv[12]=b3.x;Bv[13]=b3.y;Bv[14]=b3.z;Bv[15]=b3.w;
      Cv[0]=c0.x;Cv[1]=c0.y;Cv[2]=c0.z;Cv[3]=c0.w; Cv[4]=c1.x;Cv[5]=c1.y;Cv[6]=c1.z;Cv[7]=c1.w;
      Cv[8]=c2.x;Cv[9]=c2.y;Cv[10]=c2.z;Cv[11]=c2.w; Cv[12]=c3.x;Cv[13]=c3.y;Cv[14]=c3.z;Cv[15]=c3.w;
      float rr[16];
      if (fastu){
        float r1 = ex2(-dtv*LOG2E);
        float r2=r1*r1;
        float r3=r2*r1, r4=r2*r2;
        float r5=r4*r1, r6=r4*r2, r7=r4*r3, r8=r4*r4;
        rr[0]=r1; rr[1]=r2; rr[2]=r3; rr[3]=r4;
        rr[4]=r5; rr[5]=r6; rr[6]=r7; rr[7]=r8;
        rr[8]=r8*r1; rr[9]=r8*r2; rr[10]=r8*r3; rr[11]=r8*r4;
        rr[12]=r8*r5; rr[13]=r8*r6; rr[14]=r8*r7; rr[15]=r8*r8;
      } else {
        #pragma unroll
        for (int ss=0;ss<16;ss++) rr[ss] = ex2(dtv*A2[ss]);
      }
      float y0 = 0.f, y1 = 0.f;
      #pragma unroll
      for (int ss=0;ss<16;ss+=2){
        h[ss]   = rr[ss]*h[ss]     + dtx*Bv[ss];
        h[ss+1] = rr[ss+1]*h[ss+1] + dtx*Bv[ss+1];
        y0 += h[ss]*Cv[ss];
        y1 += h[ss+1]*Cv[ss+1];
      }
      float g0 = (y0+y1) + xv*Dv;
      unsigned short hh,lo2; split2(g0,hh,lo2);
      s_hi[t*264+d]=hh; s_lo[t*264+d]=lo2;
      q0=nq0; q1=nq1; xh=nxh; xl=nxl;
    }
  }
  __syncthreads();

  // ---- phase 5: z-half GEMM (recompute) + fused silu-gating in place.
  {
    bf16x8 ah[2][4], al[2][4];
    {
      int row = ml; // mt=0
      #pragma unroll
      for (int kk=0;kk<4;kk++){
        ah[0][kk] = *(const bf16x8*)&phi[(size_t)row*128 + kk*32 + quad*8];
        al[0][kk] = *(const bf16x8*)&plo[(size_t)row*128 + kk*32 + quad*8];
      }
    }
    #pragma unroll
    for (int mt=0; mt<5; ++mt){
      const int cur = mt&1, nxt = cur^1;
      if (mt<4){
        int row = (mt+1)*16+ml; if (row>64) row=64;
        #pragma unroll
        for (int kk=0;kk<4;kk++){
          ah[nxt][kk] = *(const bf16x8*)&phi[(size_t)row*128 + kk*32 + quad*8];
          al[nxt][kk] = *(const bf16x8*)&plo[(size_t)row*128 + kk*32 + quad*8];
        }
      }
      #pragma unroll
      for (int j=0;j<4;j++){
        int nt = w + j*4;
        f32x4 acc={0.f,0.f,0.f,0.f};
        #pragma unroll
        for (int kk=0;kk<4;kk++){
          bf16x8 b = *(const bf16x8*)&INF[((size_t)((16+nt)*4+kk))*512 + lane*8];
          acc = mfma16(ah[cur][kk],b,mfma16(al[cur][kk],b,acc));
        }
        int d = nt*16+ml;
        #pragma unroll
        for (int r=0;r<4;r++){
          int t = mt*16+quad*4+r;
          if (t<NP){
            float g0 = b2f(s_hi[t*264+d]) + b2f(s_lo[t*264+d]);
            float zv = acc[r];
            float g = g0 * zv * sigm(zv);
            unsigned short hh,lo2; split2(g,hh,lo2);
            s_hi[t*264+d]=hh; s_lo[t*264+d]=lo2;
          }
        }
      }
    }
  }
  __syncthreads();

  // ---- phase 6: out_proj (M=65,N=128,K=256) split-A -> pout planes.
  {
    f32x4 acc[5][2];
    #pragma unroll
    for (int mt=0;mt<5;mt++){
      #pragma unroll
      for (int p2=0;p2<2;p2++){ f32x4 z={0.f,0.f,0.f,0.f}; acc[mt][p2]=z; }
    }
    bf16x8 bpre[2][2];
    bpre[0][0] = *(const bf16x8*)&OPF[((size_t)((w*2+0)*8+0))*512 + lane*8];
    bpre[0][1] = *(const bf16x8*)&OPF[((size_t)((w*2+1)*8+0))*512 + lane*8];
    #pragma unroll
    for (int kk=0;kk<8;kk++){
      const int cur = kk&1, nxt = cur^1;
      if (kk<7){
        bpre[nxt][0] = *(const bf16x8*)&OPF[((size_t)((w*2+0)*8+kk+1))*512 + lane*8];
        bpre[nxt][1] = *(const bf16x8*)&OPF[((size_t)((w*2+1)*8+kk+1))*512 + lane*8];
      }
      bf16x8 ah[5], al[5];
      #pragma unroll
      for (int mt=0;mt<5;mt++){
        int row = mt*16+ml; if (row>64) row=64;
        ah[mt] = *(const bf16x8*)&s_hi[row*264 + kk*32 + quad*8];
        al[mt] = *(const bf16x8*)&s_lo[row*264 + kk*32 + quad*8];
      }
      #pragma unroll
      for (int mt=0;mt<5;mt++)
        acc[mt][0] = mfma16(ah[mt],bpre[cur][0],mfma16(al[mt],bpre[cur][0],acc[mt][0]));
      #pragma unroll
      for (int mt=0;mt<5;mt++)
        acc[mt][1] = mfma16(ah[mt],bpre[cur][1],mfma16(al[mt],bpre[cur][1],acc[mt][1]));
    }
    #pragma unroll
    for (int p2=0;p2<2;p2++){
      int dm = (w*2+p2)*16+ml;
      #pragma unroll
      for (int mt=0;mt<5;mt++){
        #pragma unroll
        for (int r=0;r<4;r++){
          int t = mt*16+quad*4+r;
          if (t<NP){
            unsigned short hh,lo2; split2(acc[mt][p2][r],hh,lo2);
            pout[(size_t)n*HNF + t*128 + dm] = hh;
            pout[(size_t)n*HNF + t*128 + dm + LOPL] = lo2;
          }
        }
      }
    }
  }
}

// =====================================================================
// head GEMM, K-split x4: coalesced HDF B, SIMPLE loop (compiler schedules;
// hand-pipelined while-loop version measured slower -- round 5 vs 7 tails).
// =====================================================================
__global__ void k_headp(const float* __restrict__ ws, float* __restrict__ hacc)
{
  const int blk = blockIdx.x;
  const int p = blk & 3, tile = blk >> 2;
  const int nt = tile%6, mt = tile/6;
  const int tid = threadIdx.x, w = tid>>6, lane = tid&63, ml = lane&15, quad = lane>>4;
  const unsigned short* pa_hi = (const unsigned short*)(ws+OFF_PA);
  const unsigned short* pa_lo = pa_hi + LOPL;
  const unsigned short* HDF = (const unsigned short*)(ws+OFF_HDF);
  __shared__ float red[4][64][4];

  f32x4 acc={0.f,0.f,0.f,0.f};
  const size_t abase = (size_t)(mt*16+ml)*HNF + quad*8;
  for (int i=w; i<65; i+=4){
    int kk = p*65 + i;
    bf16x8 ah = *(const bf16x8*)(pa_hi + abase + (size_t)kk*32);
    bf16x8 al = *(const bf16x8*)(pa_lo + abase + (size_t)kk*32);
    bf16x8 b = *(const bf16x8*)&HDF[((size_t)(nt*260+kk))*512 + lane*8];
    acc = mfma16(ah,b,mfma16(al,b,acc));
  }
  #pragma unroll
  for (int r=0;r<4;r++) red[w][lane][r]=acc[r];
  __syncthreads();
  if (w==0){
    #pragma unroll
    for (int r=0;r<4;r++){
      float s = red[0][lane][r]+red[1][lane][r]+red[2][lane][r]+red[3][lane][r];
      hacc[((size_t)tile*4 + p)*256 + lane*4 + r] = s;
    }
  }
}

// =====================================================================
// final: sum 4 partials + de-norm + write out. 192 blocks x 64 threads.
// =====================================================================
__global__ void k_fin(const float* __restrict__ ws, void* __restrict__ out)
{
  const int tile = blockIdx.x;
  const int nt = tile%6, mt = tile/6;
  const int lane = threadIdx.x, ml = lane&15, quad = lane>>4;
  const float* hacc = ws + OFF_HACC;
  const int isbf = ws[OFF_FLAG]!=0.f;
  #pragma unroll
  for (int r=0;r<4;r++){
    size_t base = (size_t)tile*4*256 + lane*4 + r;
    float s = hacc[base] + hacc[base+256] + hacc[base+512] + hacc[base+768];
    int nseq = mt*16 + quad*4 + r;
    int pred = nt*16 + ml;
    float val = s*ws[OFF_STD+nseq] + ws[OFF_MEAN+nseq];
    size_t o = ((size_t)(nseq>>4)*96 + pred)*16 + (nseq&15);
    if (isbf) ((unsigned short*)out)[o] = f2b(val);
    else      ((float*)out)[o] = val;
  }
}

extern "C" void kernel_launch(void* const* d_in, const int* in_sizes, int n_in,
                              void* d_out, int out_size, void* d_ws, size_t ws_size,
                              hipStream_t stream)
{
  (void)in_sizes; (void)n_in; (void)out_size; (void)ws_size;
  float* ws = (float*)d_ws;
  const void* x_enc = d_in[0];
  const void* pe_w  = d_in[2];  const void* pe_b  = d_in[3];
  const void* in_w  = d_in[4];  const void* conv_w= d_in[5];
  const void* conv_b= d_in[6];  const void* xp_w  = d_in[7];
  const void* dtp_w = d_in[8];  const void* dtp_b = d_in[9];
  const void* A_log = d_in[10]; const void* Dm    = d_in[11];
  const void* op_w  = d_in[12]; const void* head_w= d_in[13];

  k_pre<<<NPREP+NSEQ,256,0,stream>>>(x_enc,pe_w,pe_b,in_w,conv_w,conv_b,xp_w,
                                     dtp_b,A_log,Dm,op_w,head_w,ws);
  unsigned short* pa = (unsigned short*)(ws+OFF_PA);
  unsigned short* pb = (unsigned short*)(ws+OFF_PB);
  k_layer<<<NSEQ,256,0,stream>>>(0,pa,pb,ws,dtp_w);
  k_layer<<<NSEQ,256,0,stream>>>(1,pb,pa,ws,dtp_w);
  k_headp<<<768,256,0,stream>>>(ws, ws+OFF_HACC);
  k_fin<<<192,64,0,stream>>>(ws, d_out);
}

// Round 11
// 254.200 us; speedup vs baseline: 1.2702x; 1.0457x over previous
//
#include <hip/hip_runtime.h>

typedef __attribute__((ext_vector_type(8))) short bf16x8;
typedef __attribute__((ext_vector_type(8))) unsigned short u16x8;
typedef __attribute__((ext_vector_type(4))) float f32x4;

#define DEV static __device__ __forceinline__

// ---- config ----
constexpr int DM   = 128;
constexpr int DIN  = 256;
constexpr int NP   = 65;      // NPATCH
constexpr int NSEQ = 512;     // B*C
constexpr int HNF  = 8320;    // DM*NP
constexpr int LOPL = NSEQ*HNF;   // shorts between hi and lo planes

// ---- ws layout (float offsets) ----
// LIVENESS NOTE: PB region is fully clobbered by k_layer(0) output; nothing
// that must survive past k_layer(0) may live there except k_headp partials
// (written afterwards). No persistent counters exist in this layout.
constexpr size_t OFF_FLAG = 0;
constexpr size_t OFF_MEAN = 16;                       // 512
constexpr size_t OFF_STD  = OFF_MEAN + 512;           // 512
constexpr size_t OFF_ANEG = OFF_STD  + 512;           // 2*256*16 = 8192
constexpr size_t OFF_CONVW= OFF_ANEG + 8192;          // 2048
constexpr size_t OFF_CONVB= OFF_CONVW+ 2048;          // 512
constexpr size_t OFF_DTPB = OFF_CONVB+ 512;           // 512
constexpr size_t OFF_DD   = OFF_DTPB + 512;           // 512
constexpr size_t OFF_PEWT = OFF_DD   + 512;           // 2048
constexpr size_t OFF_PEB  = OFF_PEWT + 2048;          // 128
constexpr size_t OFF_INF  = OFF_PEB  + 128;           // 131072 shorts = 65536 f
constexpr size_t OFF_XPF  = OFF_INF  + 65536;         // 24576 shorts = 12288 f
constexpr size_t OFF_OPF  = OFF_XPF  + 12288;         // 65536 shorts = 32768 f
constexpr size_t OFF_HDF  = OFF_OPF  + 32768;         // 798720 shorts = 399360 f
constexpr size_t OFF_PA   = OFF_HDF  + 399360;        // hi+lo planes: 2*NSEQ*HNF shorts
constexpr size_t OFF_PB   = OFF_PA   + (size_t)NSEQ*HNF;
constexpr size_t OFF_HACC = OFF_PB;                   // head partials (written after layers)
// total = OFF_PB + NSEQ*HNF = 9,044,624 floats ~= 36.2 MB

DEV float b2f(unsigned short u){ union{unsigned v; float f;} x; x.v = ((unsigned)u)<<16; return x.f; }
DEV unsigned short f2b(float f){
  union{float f32; unsigned u;} x; x.f32 = f;
  unsigned r = x.u + 0x7fffu + ((x.u>>16)&1u);
  return (unsigned short)(r>>16);
}
DEV void split2(float v, unsigned short& h, unsigned short& l){
  h = f2b(v); l = f2b(v - b2f(h));
}
DEV float load_in(const void* p, size_t i, int isbf){
  return isbf ? b2f(((const unsigned short*)p)[i]) : ((const float*)p)[i];
}
DEV f32x4 mfma16(bf16x8 a, bf16x8 b, f32x4 c){
  return __builtin_amdgcn_mfma_f32_16x16x32_bf16(a,b,c,0,0,0);
}
constexpr float LOG2E = 1.4426950408889634f;
constexpr float LN2   = 0.6931471805599453f;
DEV float ex2(float x){ float r; asm("v_exp_f32 %0, %1" : "=v"(r) : "v"(x)); return r; }
DEV float lg2(float x){ float r; asm("v_log_f32 %0, %1" : "=v"(r) : "v"(x)); return r; }
DEV float frcp(float x){ float r; asm("v_rcp_f32 %0, %1" : "=v"(r) : "v"(x)); return r; }
DEV float sigm(float x){ return frcp(1.f + ex2(-x*LOG2E)); }
DEV float softplus(float x){
  float t = ex2(-fabsf(x)*LOG2E);
  return fmaxf(x,0.f) + LN2*lg2(1.f + t);
}
DEV int detect_bf16_wave(const void* x, int tid){
  const unsigned short* u = (const unsigned short*)x;
  unsigned short v = u[2*tid];
  int e = (v>>7)&0xff;
  int pred = (v==0) || (e>=100 && e<=141);
  unsigned long long m = __ballot(pred);
  return __popcll(m) >= 48;
}
// load 8 consecutive source elements (f32 or bf16) -> exact-bf16 u16x8
DEV u16x8 load8_cvt(const void* p, size_t off, int isbf){
  u16x8 o;
  if (isbf){
    o = *(const u16x8*)((const unsigned short*)p + off);   // identity (f2b∘b2f == id)
  } else {
    const float* s = (const float*)p + off;
    float4 a = *(const float4*)(s), b = *(const float4*)(s+4);
    o[0]=f2b(a.x); o[1]=f2b(a.y); o[2]=f2b(a.z); o[3]=f2b(a.w);
    o[4]=f2b(b.x); o[5]=f2b(b.y); o[6]=f2b(b.z); o[7]=f2b(b.w);
  }
  return o;
}

// =====================================================================
// fused prep + embed. repack blocks [0,NPREP), embed blocks [NPREP,NPREP+512)
// HDF repack kept (coalescing beats byte-count -- round-6 lesson).
// =====================================================================
constexpr size_t N_SMALL = 13952;                 // scalar f32 params
constexpr size_t N_IN8 = 16384, N_XP8 = 3072, N_OP8 = 8192, N_HD8 = 99840;
constexpr size_t N_BIG8 = N_IN8+N_XP8+N_OP8+N_HD8;  // 127488
constexpr int NPREP = (int)((N_SMALL + N_BIG8 + 255)/256);  // 553
__global__ void k_pre(const void* x_enc, const void* pe_w, const void* pe_b,
                      const void* in_w, const void* conv_w, const void* conv_b,
                      const void* xp_w, const void* dtp_b,
                      const void* A_log, const void* Dm, const void* op_w,
                      const void* head_w, float* __restrict__ ws)
{
  const int tid = threadIdx.x;
  __shared__ int sflag;
  __shared__ float sx[512];
  __shared__ float spe[16*128];
  __shared__ float spb[128];
  __shared__ float rs[8], rq[8], sm[2];

  if (tid < 64){
    int f = detect_bf16_wave(x_enc, tid);
    if (tid==0) sflag = f;
  }
  __syncthreads();
  const int isbf = sflag;

  if (blockIdx.x < NPREP){
    if (blockIdx.x==0 && tid==0) ws[OFF_FLAG] = (float)isbf;
    size_t i = (size_t)blockIdx.x*256 + tid;
    const size_t nA=8192, nCW=2048, nCB=512, nDB=512, nD=512, nPW=2048, nPB=128;
    if (i < N_SMALL){
      if (i < nA){ ws[OFF_ANEG+i] = -__expf(load_in(A_log,i,isbf)); return; } i -= nA;
      if (i < nCW){ ws[OFF_CONVW+i] = load_in(conv_w,i,isbf); return; } i -= nCW;
      if (i < nCB){ ws[OFF_CONVB+i] = load_in(conv_b,i,isbf); return; } i -= nCB;
      if (i < nDB){ ws[OFF_DTPB+i]  = load_in(dtp_b,i,isbf); return; } i -= nDB;
      if (i < nD){  ws[OFF_DD+i]    = load_in(Dm,i,isbf); return; } i -= nD;
      if (i < nPW){ size_t k=i>>7, dm=i&127; ws[OFF_PEWT+i]=load_in(pe_w, dm*16+k, isbf); return; } i -= nPW;
      ws[OFF_PEB+i] = load_in(pe_b,i,isbf); return;
    }
    size_t i8 = i - N_SMALL;
    if (i8 >= N_BIG8) return;
    if (i8 < N_IN8){ // in_proj: 8 shorts at frag idx i8*8; k contiguous
      size_t lane=i8&63, kk=(i8>>6)&3, nt=(i8>>8)&31, l=i8>>13;
      size_t e=nt*16+(lane&15), k0=kk*32+((lane>>4)*8);
      ((u16x8*)((unsigned short*)(ws+OFF_INF)))[i8] =
        load8_cvt(in_w, (l*512+e)*128 + k0, isbf);
      return;
    } i8 -= N_IN8;
    if (i8 < N_XP8){ // x_proj (o<40 real, else zero-pad)
      size_t lane=i8&63, kk=(i8>>6)&7; size_t rest=i8>>9;
      size_t nt=rest%3, l=rest/3;
      size_t o=nt*16+(lane&15), k0=kk*32+((lane>>4)*8);
      u16x8 v;
      if (o<40) v = load8_cvt(xp_w, (l*40+o)*256 + k0, isbf);
      else { u16x8 z = {0,0,0,0,0,0,0,0}; v = z; }
      ((u16x8*)((unsigned short*)(ws+OFF_XPF)))[i8] = v;
      return;
    } i8 -= N_XP8;
    if (i8 < N_OP8){ // out_proj
      size_t lane=i8&63, kk=(i8>>6)&7, nt=(i8>>9)&7, l=i8>>12;
      size_t dm=nt*16+(lane&15), k0=kk*32+((lane>>4)*8);
      ((u16x8*)((unsigned short*)(ws+OFF_OPF)))[i8] =
        load8_cvt(op_w, (l*128+dm)*256 + k0, isbf);
      return;
    } i8 -= N_OP8;
    { // head: B[k(8320)][pred(96)] = head_w[pred][k], [nt6][kk260]
      size_t lane=i8&63, t=i8>>6;
      size_t kk=t%260, nt=t/260;
      size_t pr=nt*16+(lane&15), k0=kk*32+((lane>>4)*8);
      ((u16x8*)((unsigned short*)(ws+OFF_HDF)))[i8] =
        load8_cvt(head_w, pr*8320 + k0, isbf);
      return;
    }
  }

  // ---------------- embed (RevIN + patch conv) ----------------
  const int n = blockIdx.x - NPREP;
  const int b = n>>4, c = n&15;

  float v0 = load_in(x_enc, ((size_t)b*512+tid)*16 + c, isbf);
  float v1 = load_in(x_enc, ((size_t)b*512+tid+256)*16 + c, isbf);
  float s = v0+v1, q = v0*v0+v1*v1;
  for (int o=32;o;o>>=1){ s += __shfl_down(s,o,64); q += __shfl_down(q,o,64); }
  const int w = tid>>6, lane = tid&63;
  if (lane==0){ rs[w]=s; rq[w]=q; }
  __syncthreads();
  if (tid==0){
    float S=rs[0]+rs[1]+rs[2]+rs[3], Q=rq[0]+rq[1]+rq[2]+rq[3];
    float mean = S*(1.f/512.f);
    float var = fmaxf(Q*(1.f/512.f)-mean*mean, 0.f);
    float sd = sqrtf(var+1e-5f);
    sm[0]=mean; sm[1]=1.f/sd;
    ws[OFF_MEAN+n]=mean; ws[OFF_STD+n]=sd;
  }
  __syncthreads();
  const float mean=sm[0], rstd=sm[1];
  sx[tid]=(v0-mean)*rstd; sx[tid+256]=(v1-mean)*rstd;
  for (int i=tid;i<2048;i+=256) spe[i]=load_in(pe_w, (size_t)(i&127)*16 + (i>>7), isbf);
  if (tid<128) spb[tid]=load_in(pe_b, tid, isbf);
  __syncthreads();

  unsigned short* pa_hi = (unsigned short*)(ws+OFF_PA);
  unsigned short* pa_lo = pa_hi + LOPL;
  for (int i=tid;i<NP*DM;i+=256){
    int t=i>>7, dm=i&127;
    float acc = spb[dm];
    int j0 = t*8-8;
    #pragma unroll
    for (int k=0;k<16;k++){ int j=j0+k; if ((unsigned)j<512u) acc += sx[j]*spe[k*128+dm]; }
    unsigned short h,lo2; split2(acc,h,lo2);
    pa_hi[(size_t)n*HNF+i] = h;
    pa_lo[(size_t)n*HNF+i] = lo2;
  }
}

// =====================================================================
// One fused Mamba layer, split-precision. block = one sequence.
// FINAL 256-thread structure (measured 74-76 us; 512-thread variants
// measured worse twice -- rounds 2 and 9: work duplication > occupancy).
// =====================================================================
__global__ __launch_bounds__(256,2)
void k_layer(int l, const unsigned short* __restrict__ pin,
             unsigned short* __restrict__ pout, float* __restrict__ ws,
             const void* __restrict__ dtp_w_raw)
{
  const int n = blockIdx.x, tid = threadIdx.x;
  const int w = tid>>6, lane = tid&63, ml = lane&15, quad = lane>>4;
  const int isbf = ws[OFF_FLAG] != 0.f;

  __shared__ __align__(16) unsigned char arena[79040];
  unsigned short* s_hi = (unsigned short*)arena;
  unsigned short* s_lo = (unsigned short*)(arena+34320);
  float* s_dbc = (float*)(arena+68640);

  const unsigned short* INF = (const unsigned short*)(ws+OFF_INF) + (size_t)l*65536;
  const unsigned short* XPF = (const unsigned short*)(ws+OFF_XPF) + (size_t)l*12288;
  const unsigned short* OPF = (const unsigned short*)(ws+OFF_OPF) + (size_t)l*32768;
  const unsigned short* phi = pin + (size_t)n*HNF;
  const unsigned short* plo = phi + LOPL;

  // ---- phase 1: in_proj xin-half (M=65,N=256,K=128), split-A -> s_hi/s_lo
  for (int pass=0; pass<2; ++pass){
    f32x4 acc[5][2];
    #pragma unroll
    for (int mt=0;mt<5;mt++){
      #pragma unroll
      for (int p2=0;p2<2;p2++){ f32x4 z={0.f,0.f,0.f,0.f}; acc[mt][p2]=z; }
    }
    bf16x8 ah[2][5], al[2][5];
    #pragma unroll
    for (int mt=0;mt<5;mt++){
      int row = mt*16+ml; if (row>64) row=64;
      ah[0][mt] = *(const bf16x8*)&phi[(size_t)row*128 + quad*8];
      al[0][mt] = *(const bf16x8*)&plo[(size_t)row*128 + quad*8];
    }
    #pragma unroll
    for (int kk=0;kk<4;kk++){
      const int cur = kk&1, nxt = cur^1;
      bf16x8 b0 = *(const bf16x8*)&INF[((size_t)((pass*8+w*2+0)*4+kk))*512 + lane*8];
      bf16x8 b1 = *(const bf16x8*)&INF[((size_t)((pass*8+w*2+1)*4+kk))*512 + lane*8];
      if (kk<3){
        #pragma unroll
        for (int mt=0;mt<5;mt++){
          int row = mt*16+ml; if (row>64) row=64;
          ah[nxt][mt] = *(const bf16x8*)&phi[(size_t)row*128 + (kk+1)*32 + quad*8];
          al[nxt][mt] = *(const bf16x8*)&plo[(size_t)row*128 + (kk+1)*32 + quad*8];
        }
      }
      #pragma unroll
      for (int mt=0;mt<5;mt++)
        acc[mt][0] = mfma16(ah[cur][mt],b0,mfma16(al[cur][mt],b0,acc[mt][0]));
      #pragma unroll
      for (int mt=0;mt<5;mt++)
        acc[mt][1] = mfma16(ah[cur][mt],b1,mfma16(al[cur][mt],b1,acc[mt][1]));
    }
    #pragma unroll
    for (int p2=0;p2<2;p2++){
      int e = (pass*8 + w*2 + p2)*16 + ml;
      #pragma unroll
      for (int mt=0;mt<5;mt++){
        #pragma unroll
        for (int r=0;r<4;r++){
          int t = mt*16+quad*4+r;
          if (t<NP){
            unsigned short h,lo2; split2(acc[mt][p2][r],h,lo2);
            s_hi[t*264+e]=h; s_lo[t*264+e]=lo2;
          }
        }
      }
    }
  }
  __syncthreads();

  // ---- phase 2: causal depthwise conv (k=4) + SiLU in place; thread=d.
  {
    const int d = tid;
    const float4 wv = ((const float4*)(ws+OFF_CONVW))[l*256+d];
    const float bb = ws[OFF_CONVB + l*256+d];
    float x0=0.f,x1=0.f,x2=0.f;
    int t = 0;
    for (; t+4<=NP; t+=4){
      float xi0 = b2f(s_hi[(t+0)*264+d]) + b2f(s_lo[(t+0)*264+d]);
      float xi1 = b2f(s_hi[(t+1)*264+d]) + b2f(s_lo[(t+1)*264+d]);
      float xi2 = b2f(s_hi[(t+2)*264+d]) + b2f(s_lo[(t+2)*264+d]);
      float xi3 = b2f(s_hi[(t+3)*264+d]) + b2f(s_lo[(t+3)*264+d]);
      float v0 = bb + wv.x*x0  + wv.y*x1  + wv.z*x2  + wv.w*xi0;
      float v1 = bb + wv.x*x1  + wv.y*x2  + wv.z*xi0 + wv.w*xi1;
      float v2 = bb + wv.x*x2  + wv.y*xi0 + wv.z*xi1 + wv.w*xi2;
      float v3 = bb + wv.x*xi0 + wv.y*xi1 + wv.z*xi2 + wv.w*xi3;
      x0=xi1; x1=xi2; x2=xi3;
      float s0 = v0*sigm(v0), s1 = v1*sigm(v1), s2 = v2*sigm(v2), s3 = v3*sigm(v3);
      unsigned short h,lo2;
      split2(s0,h,lo2); s_hi[(t+0)*264+d]=h; s_lo[(t+0)*264+d]=lo2;
      split2(s1,h,lo2); s_hi[(t+1)*264+d]=h; s_lo[(t+1)*264+d]=lo2;
      split2(s2,h,lo2); s_hi[(t+2)*264+d]=h; s_lo[(t+2)*264+d]=lo2;
      split2(s3,h,lo2); s_hi[(t+3)*264+d]=h; s_lo[(t+3)*264+d]=lo2;
    }
    for (; t<NP; ++t){
      float xi = b2f(s_hi[t*264+d]) + b2f(s_lo[t*264+d]);
      float v = bb + wv.x*x0 + wv.y*x1 + wv.z*x2 + wv.w*xi;
      x0=x1; x1=x2; x2=xi;
      float sv = v * sigm(v);
      unsigned short h,lo2; split2(sv,h,lo2);
      s_hi[t*264+d]=h; s_lo[t*264+d]=lo2;
    }
  }
  __syncthreads();

  // ---- phase 3: x_proj (M=65,N=48(40),K=256) split-A -> s_dbc fp32
  for (int tile=w; tile<15; tile+=4){
    int mt=tile/3, nt=tile%3;
    f32x4 acc={0.f,0.f,0.f,0.f};
    #pragma unroll
    for (int kk=0;kk<8;kk++){
      int row = mt*16+ml; if (row>64) row=64;
      bf16x8 ah = *(const bf16x8*)&s_hi[row*264 + kk*32 + quad*8];
      bf16x8 al = *(const bf16x8*)&s_lo[row*264 + kk*32 + quad*8];
      bf16x8 b  = *(const bf16x8*)&XPF[((size_t)(nt*8+kk))*512 + lane*8];
      acc = mfma16(ah,b,mfma16(al,b,acc));
    }
    int o = nt*16+ml;
    #pragma unroll
    for (int r=0;r<4;r++){
      int t=mt*16+quad*4+r;
      if (t<NP && o<40) s_dbc[t*40+o] = acc[r];
    }
  }
  __syncthreads();

  // ---- phase 4: dt (fp32) + selective scan + D-skip; thread=d.
  {
    const int d = tid;
    float A2[16];
    {
      const float4* ap = (const float4*)(ws+OFF_ANEG) + ((size_t)l*256+d)*4;
      #pragma unroll
      for (int qq=0;qq<4;qq++){
        float4 t4 = ap[qq];
        A2[qq*4]=t4.x*LOG2E; A2[qq*4+1]=t4.y*LOG2E; A2[qq*4+2]=t4.z*LOG2E; A2[qq*4+3]=t4.w*LOG2E;
      }
    }
    int fastbit = 1;
    #pragma unroll
    for (int ss=0;ss<16;ss++){
      float ex = -(float)(ss+1)*LOG2E;
      fastbit &= (fabsf(A2[ss]-ex) <= 1e-4f*(float)(ss+1)) ? 1 : 0;
    }
    const int fastu = __all(fastbit);
    const float Dv = ws[OFF_DD + l*256+d];
    const float bias = ws[OFF_DTPB + l*256+d];
    float wdt[8];
    #pragma unroll
    for (int r=0;r<8;r++) wdt[r] = load_in(dtp_w_raw, ((size_t)l*256+d)*8+r, isbf);
    float h[16];
    #pragma unroll
    for (int ss=0;ss<16;ss++) h[ss]=0.f;

    float4 q0 = *(const float4*)&s_dbc[0];
    float4 q1 = *(const float4*)&s_dbc[4];
    float xh = b2f(s_hi[d]), xl = b2f(s_lo[d]);

    for (int t=0;t<NP;t++){
      const float* row = &s_dbc[t*40];
      float xv = xh + xl;
      float4 b0=*(const float4*)(row+8),  b1=*(const float4*)(row+12),
             b2v=*(const float4*)(row+16), b3=*(const float4*)(row+20);
      float4 c0=*(const float4*)(row+24), c1=*(const float4*)(row+28),
             c2=*(const float4*)(row+32), c3=*(const float4*)(row+36);
      float4 nq0, nq1; float nxh=0.f, nxl=0.f;
      if (t+1<NP){
        const float* nrow = &s_dbc[(t+1)*40];
        nq0 = *(const float4*)(nrow);
        nq1 = *(const float4*)(nrow+4);
        nxh = b2f(s_hi[(t+1)*264+d]); nxl = b2f(s_lo[(t+1)*264+d]);
      }
      float p0 = q0.x*wdt[0] + q0.y*wdt[1];
      float p1 = q0.z*wdt[2] + q0.w*wdt[3];
      float p2 = q1.x*wdt[4] + q1.y*wdt[5];
      float p3 = q1.z*wdt[6] + q1.w*wdt[7];
      float din = (bias + p0 + p1) + (p2 + p3);
      float dtv = softplus(din);
      float dtx = dtv*xv;
      float Bv[16], Cv[16];
      Bv[0]=b0.x;Bv[1]=b0.y;Bv[2]=b0.z;Bv[3]=b0.w; Bv[4]=b1.x;Bv[5]=b1.y;Bv[6]=b1.z;Bv[7]=b1.w;
      Bv[8]=b2v.x;Bv[9]=b2v.y;Bv[10]=b2v.z;Bv[11]=b2v.w; Bv[12]=b3.x;Bv[13]=b3.y;Bv[14]=b3.z;Bv[15]=b3.w;
      Cv[0]=c0.x;Cv[1]=c0.y;Cv[2]=c0.z;Cv[3]=c0.w; Cv[4]=c1.x;Cv[5]=c1.y;Cv[6]=c1.z;Cv[7]=c1.w;
      Cv[8]=c2.x;Cv[9]=c2.y;Cv[10]=c2.z;Cv[11]=c2.w; Cv[12]=c3.x;Cv[13]=c3.y;Cv[14]=c3.z;Cv[15]=c3.w;
      float rr[16];
      if (fastu){
        float r1 = ex2(-dtv*LOG2E);
        float r2=r1*r1;
        float r3=r2*r1, r4=r2*r2;
        float r5=r4*r1, r6=r4*r2, r7=r4*r3, r8=r4*r4;
        rr[0]=r1; rr[1]=r2; rr[2]=r3; rr[3]=r4;
        rr[4]=r5; rr[5]=r6; rr[6]=r7; rr[7]=r8;
        rr[8]=r8*r1; rr[9]=r8*r2; rr[10]=r8*r3; rr[11]=r8*r4;
        rr[12]=r8*r5; rr[13]=r8*r6; rr[14]=r8*r7; rr[15]=r8*r8;
      } else {
        #pragma unroll
        for (int ss=0;ss<16;ss++) rr[ss] = ex2(dtv*A2[ss]);
      }
      float y0 = 0.f, y1 = 0.f;
      #pragma unroll
      for (int ss=0;ss<16;ss+=2){
        h[ss]   = rr[ss]*h[ss]     + dtx*Bv[ss];
        h[ss+1] = rr[ss+1]*h[ss+1] + dtx*Bv[ss+1];
        y0 += h[ss]*Cv[ss];
        y1 += h[ss+1]*Cv[ss+1];
      }
      float g0 = (y0+y1) + xv*Dv;
      unsigned short hh,lo2; split2(g0,hh,lo2);
      s_hi[t*264+d]=hh; s_lo[t*264+d]=lo2;
      q0=nq0; q1=nq1; xh=nxh; xl=nxl;
    }
  }
  __syncthreads();

  // ---- phase 5: z-half GEMM (recompute) + fused silu-gating in place.
  {
    bf16x8 ah[2][4], al[2][4];
    {
      int row = ml; // mt=0
      #pragma unroll
      for (int kk=0;kk<4;kk++){
        ah[0][kk] = *(const bf16x8*)&phi[(size_t)row*128 + kk*32 + quad*8];
        al[0][kk] = *(const bf16x8*)&plo[(size_t)row*128 + kk*32 + quad*8];
      }
    }
    #pragma unroll
    for (int mt=0; mt<5; ++mt){
      const int cur = mt&1, nxt = cur^1;
      if (mt<4){
        int row = (mt+1)*16+ml; if (row>64) row=64;
        #pragma unroll
        for (int kk=0;kk<4;kk++){
          ah[nxt][kk] = *(const bf16x8*)&phi[(size_t)row*128 + kk*32 + quad*8];
          al[nxt][kk] = *(const bf16x8*)&plo[(size_t)row*128 + kk*32 + quad*8];
        }
      }
      #pragma unroll
      for (int j=0;j<4;j++){
        int nt = w + j*4;
        f32x4 acc={0.f,0.f,0.f,0.f};
        #pragma unroll
        for (int kk=0;kk<4;kk++){
          bf16x8 b = *(const bf16x8*)&INF[((size_t)((16+nt)*4+kk))*512 + lane*8];
          acc = mfma16(ah[cur][kk],b,mfma16(al[cur][kk],b,acc));
        }
        int d = nt*16+ml;
        #pragma unroll
        for (int r=0;r<4;r++){
          int t = mt*16+quad*4+r;
          if (t<NP){
            float g0 = b2f(s_hi[t*264+d]) + b2f(s_lo[t*264+d]);
            float zv = acc[r];
            float g = g0 * zv * sigm(zv);
            unsigned short hh,lo2; split2(g,hh,lo2);
            s_hi[t*264+d]=hh; s_lo[t*264+d]=lo2;
          }
        }
      }
    }
  }
  __syncthreads();

  // ---- phase 6: out_proj (M=65,N=128,K=256) split-A -> pout planes.
  {
    f32x4 acc[5][2];
    #pragma unroll
    for (int mt=0;mt<5;mt++){
      #pragma unroll
      for (int p2=0;p2<2;p2++){ f32x4 z={0.f,0.f,0.f,0.f}; acc[mt][p2]=z; }
    }
    bf16x8 bpre[2][2];
    bpre[0][0] = *(const bf16x8*)&OPF[((size_t)((w*2+0)*8+0))*512 + lane*8];
    bpre[0][1] = *(const bf16x8*)&OPF[((size_t)((w*2+1)*8+0))*512 + lane*8];
    #pragma unroll
    for (int kk=0;kk<8;kk++){
      const int cur = kk&1, nxt = cur^1;
      if (kk<7){
        bpre[nxt][0] = *(const bf16x8*)&OPF[((size_t)((w*2+0)*8+kk+1))*512 + lane*8];
        bpre[nxt][1] = *(const bf16x8*)&OPF[((size_t)((w*2+1)*8+kk+1))*512 + lane*8];
      }
      bf16x8 ah[5], al[5];
      #pragma unroll
      for (int mt=0;mt<5;mt++){
        int row = mt*16+ml; if (row>64) row=64;
        ah[mt] = *(const bf16x8*)&s_hi[row*264 + kk*32 + quad*8];
        al[mt] = *(const bf16x8*)&s_lo[row*264 + kk*32 + quad*8];
      }
      #pragma unroll
      for (int mt=0;mt<5;mt++)
        acc[mt][0] = mfma16(ah[mt],bpre[cur][0],mfma16(al[mt],bpre[cur][0],acc[mt][0]));
      #pragma unroll
      for (int mt=0;mt<5;mt++)
        acc[mt][1] = mfma16(ah[mt],bpre[cur][1],mfma16(al[mt],bpre[cur][1],acc[mt][1]));
    }
    #pragma unroll
    for (int p2=0;p2<2;p2++){
      int dm = (w*2+p2)*16+ml;
      #pragma unroll
      for (int mt=0;mt<5;mt++){
        #pragma unroll
        for (int r=0;r<4;r++){
          int t = mt*16+quad*4+r;
          if (t<NP){
            unsigned short hh,lo2; split2(acc[mt][p2][r],hh,lo2);
            pout[(size_t)n*HNF + t*128 + dm] = hh;
            pout[(size_t)n*HNF + t*128 + dm + LOPL] = lo2;
          }
        }
      }
    }
  }
}

// =====================================================================
// head GEMM restructured: block = (mt, p) with ALL 6 nt tiles per block.
// A (PA planes) read exactly ONCE total (was 6x re-read = ~102 MB);
// B (HDF 1.6 MB) is L2-resident. K-split deepens 4->8: grid 256 = 1
// block/CU, 8 waves. Partials -> OFF_HACC (8 per tile).
// =====================================================================
__global__ __launch_bounds__(512,2)
void k_headp(const float* __restrict__ ws, float* __restrict__ hacc)
{
  const int blk = blockIdx.x;            // 256 = 32 mt x 8 p
  const int p = blk & 7, mt = blk >> 3;
  const int tid = threadIdx.x, w = tid>>6, lane = tid&63, ml = lane&15, quad = lane>>4;
  const int base  = (p<4) ? p*33 : 132 + (p-4)*32;   // kk-slice start
  const int count = (p<4) ? 33 : 32;                 // kk-slice length (sum=260)
  const unsigned short* pa_hi = (const unsigned short*)(ws+OFF_PA);
  const unsigned short* pa_lo = pa_hi + LOPL;
  const unsigned short* HDF = (const unsigned short*)(ws+OFF_HDF);
  __shared__ float red[8][64][4];

  f32x4 acc[6];
  #pragma unroll
  for (int nt=0;nt<6;nt++){ f32x4 z={0.f,0.f,0.f,0.f}; acc[nt]=z; }

  const size_t abase = (size_t)(mt*16+ml)*HNF + quad*8;
  for (int i=w; i<count; i+=8){
    const int kk = base + i;
    bf16x8 ah = *(const bf16x8*)(pa_hi + abase + (size_t)kk*32);
    bf16x8 al = *(const bf16x8*)(pa_lo + abase + (size_t)kk*32);
    #pragma unroll
    for (int nt=0;nt<6;nt++){
      bf16x8 b = *(const bf16x8*)&HDF[((size_t)(nt*260+kk))*512 + lane*8];
      acc[nt] = mfma16(ah,b,mfma16(al,b,acc[nt]));
    }
  }

  // cross-wave reduction, one nt at a time (red reused)
  for (int nt=0;nt<6;nt++){
    #pragma unroll
    for (int r=0;r<4;r++) red[w][lane][r] = acc[nt][r];
    __syncthreads();
    if (w==0){
      #pragma unroll
      for (int r=0;r<4;r++){
        float s = red[0][lane][r]+red[1][lane][r]+red[2][lane][r]+red[3][lane][r]
                + red[4][lane][r]+red[5][lane][r]+red[6][lane][r]+red[7][lane][r];
        hacc[((size_t)(mt*6+nt)*8 + p)*256 + lane*4 + r] = s;
      }
    }
    __syncthreads();   // before red is overwritten for next nt
  }
}

// =====================================================================
// final: sum 8 partials + de-norm + write out. 192 blocks x 64 threads.
// =====================================================================
__global__ void k_fin(const float* __restrict__ ws, void* __restrict__ out)
{
  const int tile = blockIdx.x;
  const int nt = tile%6, mt = tile/6;
  const int lane = threadIdx.x, ml = lane&15, quad = lane>>4;
  const float* hacc = ws + OFF_HACC;
  const int isbf = ws[OFF_FLAG]!=0.f;
  #pragma unroll
  for (int r=0;r<4;r++){
    size_t base = (size_t)tile*8*256 + lane*4 + r;
    float s = 0.f;
    #pragma unroll
    for (int p=0;p<8;p++) s += hacc[base + (size_t)p*256];
    int nseq = mt*16 + quad*4 + r;
    int pred = nt*16 + ml;
    float val = s*ws[OFF_STD+nseq] + ws[OFF_MEAN+nseq];
    size_t o = ((size_t)(nseq>>4)*96 + pred)*16 + (nseq&15);
    if (isbf) ((unsigned short*)out)[o] = f2b(val);
    else      ((float*)out)[o] = val;
  }
}

extern "C" void kernel_launch(void* const* d_in, const int* in_sizes, int n_in,
                              void* d_out, int out_size, void* d_ws, size_t ws_size,
                              hipStream_t stream)
{
  (void)in_sizes; (void)n_in; (void)out_size; (void)ws_size;
  float* ws = (float*)d_ws;
  const void* x_enc = d_in[0];
  const void* pe_w  = d_in[2];  const void* pe_b  = d_in[3];
  const void* in_w  = d_in[4];  const void* conv_w= d_in[5];
  const void* conv_b= d_in[6];  const void* xp_w  = d_in[7];
  const void* dtp_w = d_in[8];  const void* dtp_b = d_in[9];
  const void* A_log = d_in[10]; const void* Dm    = d_in[11];
  const void* op_w  = d_in[12]; const void* head_w= d_in[13];

  k_pre<<<NPREP+NSEQ,256,0,stream>>>(x_enc,pe_w,pe_b,in_w,conv_w,conv_b,xp_w,
                                     dtp_b,A_log,Dm,op_w,head_w,ws);
  unsigned short* pa = (unsigned short*)(ws+OFF_PA);
  unsigned short* pb = (unsigned short*)(ws+OFF_PB);
  k_layer<<<NSEQ,256,0,stream>>>(0,pa,pb,ws,dtp_w);
  k_layer<<<NSEQ,256,0,stream>>>(1,pb,pa,ws,dtp_w);
  k_headp<<<256,512,0,stream>>>(ws, ws+OFF_HACC);
  k_fin<<<192,64,0,stream>>>(ws, d_out);
}